// Round 12
// baseline (3155.699 us; speedup 1.0000x reference)
//
#include <hip/hip_runtime.h>
#include <hip/hip_bf16.h>

typedef __hip_bfloat16 bf16;
typedef unsigned short u16;
typedef __attribute__((ext_vector_type(8))) short s16x8;   // 8 bf16 (4 VGPRs) MFMA frag
typedef __attribute__((ext_vector_type(4))) float f32x4;   // MFMA accumulator

#define B_ 512
#define T_ 150
#define S_ 151
#define D_ 256
#define H_ 8
#define HD_ 32
#define FF_ 1024
#define NC_ 4
#define DEPTH_ 6
#define MTOT 77312            // B_*S_ = 128 * 604 = 64 * 1208
#define MT128 (MTOT / 128)    // 604
#define MT64 (MTOT / 64)      // 1208

// bf16 workspace regions (elements):
#define XOFF 0
#define C1OFF (MTOT * D_)               // x: MTOT*256
#define C2OFF (C1OFF + MTOT * FF_)      // c1: MTOT*1024 (qkv)
#define WSELEMS (C2OFF + MTOT * D_)     // c2: MTOT*256 (attn out)

// Transposed bf16 weights Wt[N][K], all layers, rebuilt per call:
#define QKVT_OFF 0
#define OUTT_OFF (QKVT_OFF + DEPTH_ * D_ * 768)
#define FFN1T_OFF (OUTT_OFF + DEPTH_ * D_ * D_)
#define FFN2T_OFF (FFN1T_OFF + DEPTH_ * D_ * FF_)
#define WTELEMS (FFN2T_OFF + DEPTH_ * FF_ * D_)    // 9.4 MB

// Static device memory (d_ws proved unusable rounds 1-3).
__device__ __align__(16) u16 g_ws[WSELEMS];
__device__ __align__(16) u16 g_wt[WTELEMS];
__device__ int g_f32flag;   // 1 => external buffers f32, 0 => bf16

__device__ __forceinline__ float ldf(const void* p, size_t i, int f) {
  return f ? ((const float*)p)[i] : __bfloat162float(((const bf16*)p)[i]);
}
__device__ __forceinline__ float b2f(u16 u) {
  union { unsigned int i; float f; } v; v.i = ((unsigned int)u) << 16; return v.f;
}
__device__ __forceinline__ u16 f2b(float x) {
  bf16 h = __float2bfloat16(x);
  return *reinterpret_cast<u16*>(&h);
}

// Async global->LDS, 16 B/lane. LDS dest = wave-uniform base + lane*16.
typedef __attribute__((address_space(3))) void lds_void;
typedef const __attribute__((address_space(1))) void glob_void;
__device__ __forceinline__ void gload_lds16(const u16* g, u16* l) {
  __builtin_amdgcn_global_load_lds((glob_void*)g, (lds_void*)l, 16, 0, 0);
}

// ---------------------------------------------------------------------------
// Dtype probe on pos_embed (38656 elems ~N(0,0.02^2)) viewed as 16-bit words.
// ---------------------------------------------------------------------------
#define PROBE_N 38656
__global__ __launch_bounds__(256) void probe_kernel(const void* pe)
{
  const u16* w = (const u16*)pe;
  int susp = 0, zeroEven = 0;
  for (int k = threadIdx.x; k < PROBE_N; k += 256) {
    u16 u = w[k];
    int ex = (u >> 7) & 0xFF;
    if (ex >= 141) susp++;
    if ((k & 1) == 0 && (u & 0x7FFF) == 0) zeroEven++;
  }
  __shared__ int s_susp, s_zero;
  if (threadIdx.x == 0) { s_susp = 0; s_zero = 0; }
  __syncthreads();
  atomicAdd(&s_susp, susp);
  atomicAdd(&s_zero, zeroEven);
  __syncthreads();
  if (threadIdx.x == 0)
    g_f32flag = (s_susp > 0 || s_zero >= ((PROBE_N / 2) * 9) / 10) ? 1 : 0;
}

// ---------------------------------------------------------------------------
// Weight transpose+convert: Wt[l][n][k] = W[l][k][n] as bf16.
// ---------------------------------------------------------------------------
__global__ __launch_bounds__(256) void wtrans_kernel(const void* src, int dstOff,
                                                     int K, int N, int total)
{
  const int f = g_f32flag;
  int idx = blockIdx.x * 256 + threadIdx.x;
  if (idx >= total) return;
  int kn = K * N;
  int l = idx / kn;
  int r = idx - l * kn;
  int k = r / N;
  int n = r - k * N;
  g_wt[dstOff + (size_t)l * kn + (size_t)n * K + k] = f2b(ldf(src, idx, f));
}

// ---------------------------------------------------------------------------
// Embedding: row = blockIdx.x, writes bf16 x.
// ---------------------------------------------------------------------------
__global__ __launch_bounds__(256) void embed_kernel(
    const int* __restrict__ tt, const int* __restrict__ dids,
    const void* av, const void* dv, const void* vv,
    const void* aW, const void* ab, const void* dW, const void* db,
    const void* vW, const void* vb, const void* table, const void* pos,
    const void* cls)
{
  const int f = g_f32flag;
  u16* x = g_ws + XOFF;
  int row = blockIdx.x;
  int d = threadIdx.x;
  int b = row / S_;
  int s = row - b * S_;
  float val;
  if (s == 0) {
    val = ldf(cls, d, f);
  } else {
    int t = s - 1;
    int idx = b * T_ + t;
    int ty = tt[idx];
    if (ty == 0) {
      val = ldf(av, idx, f) * ldf(aW, d, f) + ldf(ab, d, f);
    } else if (ty == 1) {
      float acc = ldf(db, d, f) + ldf(vb, d, f);
#pragma unroll
      for (int i = 0; i < 10; i++) acc += ldf(dv, (size_t)idx * 10 + i, f) * ldf(dW, i * D_ + d, f);
#pragma unroll
      for (int i = 0; i < 3; i++) acc += ldf(vv, (size_t)idx * 3 + i, f) * ldf(vW, i * D_ + d, f);
      val = acc;
    } else if (ty == 2) {
      int did = dids[idx] & (NC_ - 1);
      val = ldf(table, (size_t)did * D_ + d, f);
    } else {
      val = 0.f;
    }
  }
  val += ldf(pos, s * D_ + d, f);
  x[(size_t)row * D_ + d] = f2b(val);
}

// ---------------------------------------------------------------------------
// MFMA GEMM (round-9 proven): 128x128, BK=64, 256 thr, global_load_lds w=16,
// xor-swizzled chunks (0 conflicts), XCD swizzle, LDS-staged epilogue.
// Used for qkv (N=768) and out-proj (N=256).
// ---------------------------------------------------------------------------
__global__ __launch_bounds__(256) void gemm_mfma(
    int aOff, int wtOff, const void* bias, size_t bOff,
    int cOff, int N, int K, int relu, int NB)
{
  const int f = g_f32flag;
  const u16* A = g_ws + aOff;
  const u16* Bt = g_wt + wtOff;
  u16* C = g_ws + cOff;
  __shared__ __align__(16) u16 sm[16384];
  const int tid = threadIdx.x;

  int gblk = blockIdx.x;
  int bm, bn;
  {
    const int full = (MT128 / 8) * 8;        // 600
    if (gblk < NB * full) {
      int per = NB * 8;
      int grp = gblk / per, rem = gblk % per;
      bm = grp * 8 + (rem & 7);
      bn = rem >> 3;
    } else {
      int id = gblk - NB * full;
      bm = full + id / NB;
      bn = id % NB;
    }
  }

  const int lane = tid & 63, wid = tid >> 6;
  const int wm = (wid >> 1) * 64, wn = (wid & 1) * 64;
  const int frow = lane & 15, quad = lane >> 4;

  const int rg = lane >> 3;
  const int ck = ((lane & 7) ^ rg) * 8;
  const u16* Ag[4]; const u16* Bg[4];
  u16 *Asl[4], *Bsl[4];
#pragma unroll
  for (int p = 0; p < 4; p++) {
    int grp = wid * 4 + p;
    int row = grp * 8 + rg;
    Ag[p] = A + (size_t)(bm * 128 + row) * K + ck;
    Bg[p] = Bt + (size_t)(bn * 128 + row) * K + ck;
    Asl[p] = &sm[grp * 512];
    Bsl[p] = &sm[8192 + grp * 512];
  }

  f32x4 acc[4][4] = {};

  for (int kt = 0; kt < K; kt += 64) {
    if (kt) __syncthreads();
#pragma unroll
    for (int p = 0; p < 4; p++) {
      gload_lds16(Ag[p] + kt, Asl[p]);
      gload_lds16(Bg[p] + kt, Bsl[p]);
    }
    __syncthreads();
#pragma unroll
    for (int s = 0; s < 2; s++) {
      s16x8 af[4], bfr[4];
      const int cfr = ((s * 4 + quad) ^ (frow & 7)) * 8;
#pragma unroll
      for (int t = 0; t < 4; t++) {
        af[t]  = *(const s16x8*)&sm[(wm + t * 16 + frow) * 64 + cfr];
        bfr[t] = *(const s16x8*)&sm[8192 + (wn + t * 16 + frow) * 64 + cfr];
      }
#pragma unroll
      for (int mt = 0; mt < 4; mt++)
#pragma unroll
        for (int nt = 0; nt < 4; nt++)
          acc[mt][nt] = __builtin_amdgcn_mfma_f32_16x16x32_bf16(af[mt], bfr[nt], acc[mt][nt], 0, 0, 0);
    }
  }

  float bv[4];
#pragma unroll
  for (int nt = 0; nt < 4; nt++)
    bv[nt] = ldf(bias, bOff + (size_t)(bn * 128 + wn + nt * 16 + frow), f);
  __syncthreads();
#pragma unroll
  for (int p = 0; p < 2; p++) {
    if ((wid >> 1) == p) {
#pragma unroll
      for (int mt = 0; mt < 4; mt++)
#pragma unroll
        for (int nt = 0; nt < 4; nt++)
#pragma unroll
          for (int r = 0; r < 4; r++) {
            int rl = (wm & 63) + mt * 16 + quad * 4 + r;
            float v = acc[mt][nt][r] + bv[nt];
            if (relu) v = fmaxf(v, 0.f);
            sm[rl * 136 + wn + nt * 16 + frow] = f2b(v);
          }
    }
    __syncthreads();
    {
      int rl = tid >> 2;
      int cq = (tid & 3) * 32;
      size_t gb = (size_t)(bm * 128 + p * 64 + rl) * N + bn * 128 + cq;
#pragma unroll
      for (int j = 0; j < 4; j++)
        *(s16x8*)(C + gb + j * 8) = *(const s16x8*)&sm[rl * 136 + cq + j * 8];
    }
    __syncthreads();
  }
}

// ---------------------------------------------------------------------------
// FUSED FFN: x = LN2(x + relu(x@W1+b1)@W2 + b2). One block per 64 rows,
// 256 thr = 4 waves. 8 ff-chunks of 128: phase A computes t=relu(x@W1c+b1)
// (K=256), t -> LDS (xor-chunk layout = proven conflict-free), phase B
// accumulates y += t@W2c (K=128) in registers. Intermediate never hits HBM
// (saves ~370 MB/layer of traffic vs split path). LDS 48KB -> 3 blocks/CU.
// sm map: [0,16384) staging (phA: x 8 grp + W1 16 grp; phB: W2 32 grp);
//         [16384,24576) t-buf 64x128 xor-chunked. Epilogue y-buf 64x272.
// ---------------------------------------------------------------------------
#define TBUF 16384
__global__ __launch_bounds__(256) void ffn_fused(
    int w1tOff, int w2tOff, const void* b1, size_t b1Off,
    const void* b2, size_t b2Off, const void* lng, const void* lnb, size_t lnOff)
{
  const int f = g_f32flag;
  const u16* X = g_ws + XOFF;
  const u16* W1 = g_wt + w1tOff;   // [1024][256]
  const u16* W2 = g_wt + w2tOff;   // [256][1024]
  __shared__ __align__(16) u16 sm[24576];
  const int tid = threadIdx.x;
  const int bm = blockIdx.x;       // 64-row tile
  const int lane = tid & 63, wid = tid >> 6;
  const int frow = lane & 15, quad = lane >> 4;
  const int wmA = (wid >> 1) * 32;     // t/y row band (32 rows)
  const int wnA = (wid & 1) * 64;      // t col band (64 of 128)
  const int wn2 = (wid & 1) * 128;     // y col band (128 of 256)
  const int rg = lane >> 3;
  const int ck = ((lane & 7) ^ rg) * 8;

  // Staging addresses.
  const u16* xg[2]; u16* xsl[2];
  const u16* w1g[4]; u16* w1sl[4];
  const u16* w2g[8]; u16* w2sl[8];
#pragma unroll
  for (int p = 0; p < 2; p++) {
    int grp = wid * 2 + p;                       // 0..8
    xg[p] = X + (size_t)(bm * 64 + grp * 8 + rg) * 256 + ck;
    xsl[p] = &sm[grp * 512];
  }
#pragma unroll
  for (int p = 0; p < 4; p++) {
    int grp = wid * 4 + p;                       // 0..16
    w1g[p] = W1 + (size_t)(grp * 8 + rg) * 256 + ck;
    w1sl[p] = &sm[4096 + grp * 512];
  }
#pragma unroll
  for (int p = 0; p < 8; p++) {
    int grp = wid * 8 + p;                       // 0..32
    w2g[p] = W2 + (size_t)(grp * 8 + rg) * 1024 + ck;
    w2sl[p] = &sm[grp * 512];
  }

  f32x4 acc2[2][8] = {};

  for (int c = 0; c < 8; c++) {
    // ---- Phase A: t[64][128] = relu(x @ W1[:, c*128..+128) + b1) ----
    f32x4 acc[2][4] = {};
    const size_t w1c = (size_t)c * 128 * 256;
    for (int kt = 0; kt < 256; kt += 64) {
      __syncthreads();   // staging region free (prev phB reads / prev iter)
#pragma unroll
      for (int p = 0; p < 2; p++) gload_lds16(xg[p] + kt, xsl[p]);
#pragma unroll
      for (int p = 0; p < 4; p++) gload_lds16(w1g[p] + w1c + kt, w1sl[p]);
      __syncthreads();
#pragma unroll
      for (int s = 0; s < 2; s++) {
        const int cfr = ((s * 4 + quad) ^ (frow & 7)) * 8;
        s16x8 af[2], bw[4];
#pragma unroll
        for (int mt = 0; mt < 2; mt++)
          af[mt] = *(const s16x8*)&sm[(wmA + mt * 16 + frow) * 64 + cfr];
#pragma unroll
        for (int nt = 0; nt < 4; nt++)
          bw[nt] = *(const s16x8*)&sm[4096 + (wnA + nt * 16 + frow) * 64 + cfr];
#pragma unroll
        for (int mt = 0; mt < 2; mt++)
#pragma unroll
          for (int nt = 0; nt < 4; nt++)
            acc[mt][nt] = __builtin_amdgcn_mfma_f32_16x16x32_bf16(af[mt], bw[nt], acc[mt][nt], 0, 0, 0);
      }
    }
    // t-write (bias + relu) into xor-chunked t-buf.
    float bv1[4];
#pragma unroll
    for (int nt = 0; nt < 4; nt++)
      bv1[nt] = ldf(b1, b1Off + c * 128 + wnA + nt * 16 + frow, f);
#pragma unroll
    for (int mt = 0; mt < 2; mt++)
#pragma unroll
      for (int nt = 0; nt < 4; nt++)
#pragma unroll
        for (int r = 0; r < 4; r++) {
          int row = wmA + mt * 16 + quad * 4 + r;
          int col = wnA + nt * 16 + frow;
          float v = fmaxf(acc[mt][nt][r] + bv1[nt], 0.f);
          sm[TBUF + row * 128 + (((col >> 3) ^ (row & 7)) * 8) + (col & 7)] = f2b(v);
        }
    __syncthreads();   // t visible across waves; phA frag reads done
    // ---- Phase B: y += t @ W2[c*128..+128, :] (K=128) ----
    for (int kt2 = 0; kt2 < 128; kt2 += 64) {
      if (kt2) __syncthreads();
#pragma unroll
      for (int p = 0; p < 8; p++) gload_lds16(w2g[p] + c * 128 + kt2, w2sl[p]);
      __syncthreads();
#pragma unroll
      for (int ks = 0; ks < 2; ks++) {
        const int cfr = ((ks * 4 + quad) ^ (frow & 7)) * 8;
        const int kc = (kt2 >> 3) + ks * 4 + quad;
        s16x8 at[2], bw[8];
#pragma unroll
        for (int mt = 0; mt < 2; mt++) {
          int row = wmA + mt * 16 + frow;
          at[mt] = *(const s16x8*)&sm[TBUF + row * 128 + ((kc ^ (row & 7)) * 8)];
        }
#pragma unroll
        for (int nt2 = 0; nt2 < 8; nt2++)
          bw[nt2] = *(const s16x8*)&sm[(wn2 + nt2 * 16 + frow) * 64 + cfr];
#pragma unroll
        for (int mt = 0; mt < 2; mt++)
#pragma unroll
          for (int nt2 = 0; nt2 < 8; nt2++)
            acc2[mt][nt2] = __builtin_amdgcn_mfma_f32_16x16x32_bf16(at[mt], bw[nt2], acc2[mt][nt2], 0, 0, 0);
      }
    }
  }

  // ---- Epilogue: y + b2 -> LDS, then x = LN(x + y) * g + b ----
  float bv2[8];
#pragma unroll
  for (int nt2 = 0; nt2 < 8; nt2++)
    bv2[nt2] = ldf(b2, b2Off + wn2 + nt2 * 16 + frow, f);
  __syncthreads();   // all phB reads done; reuse sm as y-buf 64x272
#pragma unroll
  for (int mt = 0; mt < 2; mt++)
#pragma unroll
    for (int nt2 = 0; nt2 < 8; nt2++)
#pragma unroll
      for (int r = 0; r < 4; r++) {
        int row = wmA + mt * 16 + quad * 4 + r;
        int col = wn2 + nt2 * 16 + frow;
        sm[row * 272 + col] = f2b(acc2[mt][nt2][r] + bv2[nt2]);
      }
  __syncthreads();
  {
    int rl = tid >> 2;
    int cq = (tid & 3) * 64;
    size_t rowg = (size_t)bm * 64 + rl;
    float s1 = 0.f, s2 = 0.f;
#pragma unroll
    for (int j = 0; j < 8; j++) {
      s16x8 yv = *(const s16x8*)&sm[rl * 272 + cq + j * 8];
      s16x8 xv = *(const s16x8*)(g_ws + XOFF + rowg * 256 + cq + j * 8);
#pragma unroll
      for (int e = 0; e < 8; e++) {
        float v = b2f((u16)yv[e]) + b2f((u16)xv[e]);
        s1 += v; s2 += v * v;
      }
    }
    s1 += __shfl_xor(s1, 1, 64); s2 += __shfl_xor(s2, 1, 64);
    s1 += __shfl_xor(s1, 2, 64); s2 += __shfl_xor(s2, 2, 64);
    float mean = s1 * (1.f / 256.f);
    float var = s2 * (1.f / 256.f) - mean * mean;
    float rs = rsqrtf(var + 1e-5f);
#pragma unroll
    for (int j = 0; j < 8; j++) {
      s16x8 yv = *(const s16x8*)&sm[rl * 272 + cq + j * 8];
      s16x8 xv = *(const s16x8*)(g_ws + XOFF + rowg * 256 + cq + j * 8);
      s16x8 ov;
#pragma unroll
      for (int e = 0; e < 8; e++) {
        float v = b2f((u16)yv[e]) + b2f((u16)xv[e]);
        int col = cq + j * 8 + e;
        ov[e] = (short)f2b((v - mean) * rs * ldf(lng, lnOff + col, f) + ldf(lnb, lnOff + col, f));
      }
      *(s16x8*)(g_ws + XOFF + rowg * 256 + cq + j * 8) = ov;
    }
  }
}

// ---------------------------------------------------------------------------
// MFMA attention (S=151 padded 160), VLD/PLD=170 (bank fix, round 11).
// ---------------------------------------------------------------------------
#define SP 160
#define KLD 40
#define VLD 170
#define PLD 170

__global__ __launch_bounds__(320) void attn_kernel()
{
  const u16* qkv = g_ws + C1OFF;
  u16* o = g_ws + C2OFF;
  __shared__ __align__(16) u16 Ks[SP * KLD];
  __shared__ __align__(16) u16 Vt[HD_ * VLD];
  __shared__ __align__(16) u16 Ps[5][16 * PLD];
  int bh = blockIdx.x;
  int b = bh >> 3, h = bh & 7;
  int tid = threadIdx.x;
  int lane = tid & 63, wid = tid >> 6;
  const u16* base = qkv + (size_t)b * S_ * 768;

  for (int g = tid; g < SP * 4; g += 320) {
    int j = g >> 2, d0 = (g & 3) * 8;
    s16x8 kv = {0, 0, 0, 0, 0, 0, 0, 0};
    if (j < S_) kv = *(const s16x8*)(base + (size_t)j * 768 + 256 + h * 32 + d0);
    *(s16x8*)&Ks[j * KLD + d0] = kv;
  }
  for (int g = tid; g < SP * 4; g += 320) {
    int j = g >> 2, d0 = (g & 3) * 8;
    s16x8 vv = {0, 0, 0, 0, 0, 0, 0, 0};
    if (j < S_) vv = *(const s16x8*)(base + (size_t)j * 768 + 512 + h * 32 + d0);
#pragma unroll
    for (int i = 0; i < 8; i++) Vt[(d0 + i) * VLD + j] = (u16)vv[i];
  }
  __syncthreads();

  const int frow = lane & 15;
  const int quad = lane >> 4;
  const int fk = quad * 8;
  const float scale = 0.17677669529663687f;  // 1/sqrt(32)

  for (int round = 0; round < 2; round++) {
    int mt = round * 5 + wid;
    int qrow = mt * 16 + frow;
    s16x8 aq = {0, 0, 0, 0, 0, 0, 0, 0};
    if (qrow < S_) aq = *(const s16x8*)(base + (size_t)qrow * 768 + h * 32 + fk);
    f32x4 sacc[10];
#pragma unroll
    for (int nt = 0; nt < 10; nt++) {
      s16x8 bk = *(const s16x8*)&Ks[(nt * 16 + frow) * KLD + fk];
      f32x4 z = {0.f, 0.f, 0.f, 0.f};
      sacc[nt] = __builtin_amdgcn_mfma_f32_16x16x32_bf16(aq, bk, z, 0, 0, 0);
    }
#pragma unroll
    for (int nt = 0; nt < 10; nt++) {
      int colg = nt * 16 + frow;
      float msk = (colg < S_) ? 1.f : 0.f;
#pragma unroll
      for (int r = 0; r < 4; r++)
        sacc[nt][r] = msk ? sacc[nt][r] * scale : -1e30f;
    }
    float inv[4];
#pragma unroll
    for (int r = 0; r < 4; r++) {
      float mx = -1e30f;
#pragma unroll
      for (int nt = 0; nt < 10; nt++) mx = fmaxf(mx, sacc[nt][r]);
#pragma unroll
      for (int m = 1; m < 16; m <<= 1) mx = fmaxf(mx, __shfl_xor(mx, m, 64));
      float sm2 = 0.f;
#pragma unroll
      for (int nt = 0; nt < 10; nt++) {
        float p = __expf(sacc[nt][r] - mx);
        sacc[nt][r] = p;
        sm2 += p;
      }
#pragma unroll
      for (int m = 1; m < 16; m <<= 1) sm2 += __shfl_xor(sm2, m, 64);
      inv[r] = 1.f / sm2;
    }
#pragma unroll
    for (int nt = 0; nt < 10; nt++)
#pragma unroll
      for (int r = 0; r < 4; r++)
        Ps[wid][(quad * 4 + r) * PLD + nt * 16 + frow] = f2b(sacc[nt][r]);
    f32x4 oacc[2] = {};
#pragma unroll
    for (int ks = 0; ks < 5; ks++) {
      s16x8 ap = *(const s16x8*)&Ps[wid][frow * PLD + ks * 32 + fk];
#pragma unroll
      for (int nt2 = 0; nt2 < 2; nt2++) {
        s16x8 bv = *(const s16x8*)&Vt[(nt2 * 16 + frow) * VLD + ks * 32 + fk];
        oacc[nt2] = __builtin_amdgcn_mfma_f32_16x16x32_bf16(ap, bv, oacc[nt2], 0, 0, 0);
      }
    }
#pragma unroll
    for (int nt2 = 0; nt2 < 2; nt2++)
#pragma unroll
      for (int r = 0; r < 4; r++) {
        int rowg = mt * 16 + quad * 4 + r;
        if (rowg < S_)
          o[(size_t)(b * S_ + rowg) * D_ + h * 32 + nt2 * 16 + frow] = f2b(oacc[nt2][r] * inv[r]);
      }
  }
}

// ---------------------------------------------------------------------------
// x = LN(x + y) * g + b over D=256 (used after out-proj only).
// ---------------------------------------------------------------------------
__global__ __launch_bounds__(256) void resln_kernel(int yOff,
    const void* g, size_t gOff, const void* bta, size_t btaOff)
{
  const int f = g_f32flag;
  int row = blockIdx.x * 4 + (threadIdx.x >> 6);
  int lane = threadIdx.x & 63;
  u16* xp = g_ws + XOFF + (size_t)row * D_ + lane * 4;
  const u16* yp = g_ws + yOff + (size_t)row * D_ + lane * 4;
  ushort4 xv = *(const ushort4*)xp;
  ushort4 yv = *(const ushort4*)yp;
  float r0 = b2f(xv.x) + b2f(yv.x);
  float r1 = b2f(xv.y) + b2f(yv.y);
  float r2 = b2f(xv.z) + b2f(yv.z);
  float r3 = b2f(xv.w) + b2f(yv.w);
  float s1 = r0 + r1 + r2 + r3;
  float s2 = r0 * r0 + r1 * r1 + r2 * r2 + r3 * r3;
#pragma unroll
  for (int m = 1; m < 64; m <<= 1) {
    s1 += __shfl_xor(s1, m, 64);
    s2 += __shfl_xor(s2, m, 64);
  }
  float mean = s1 * (1.f / 256.f);
  float var = s2 * (1.f / 256.f) - mean * mean;
  float rs = rsqrtf(var + 1e-5f);
  int c0 = lane * 4;
  ushort4 outv;
  outv.x = f2b((r0 - mean) * rs * ldf(g, gOff + c0 + 0, f) + ldf(bta, btaOff + c0 + 0, f));
  outv.y = f2b((r1 - mean) * rs * ldf(g, gOff + c0 + 1, f) + ldf(bta, btaOff + c0 + 1, f));
  outv.z = f2b((r2 - mean) * rs * ldf(g, gOff + c0 + 2, f) + ldf(bta, btaOff + c0 + 2, f));
  outv.w = f2b((r3 - mean) * rs * ldf(g, gOff + c0 + 3, f) + ldf(bta, btaOff + c0 + 3, f));
  *(ushort4*)xp = outv;
}

// ---------------------------------------------------------------------------
// Head: cls row -> two LNs (shared stats) -> two tiny matvecs.
// ---------------------------------------------------------------------------
__global__ __launch_bounds__(256) void head_kernel(
    const void* dg, const void* dbt, const void* dW, const void* dbias,
    const void* ag, const void* abt, const void* aW, const void* abias,
    void* out)
{
  const int f = g_f32flag;
  const u16* x = g_ws + XOFF;
  int bg = blockIdx.x;
  int tid = threadIdx.x;
  float c = b2f(x[(size_t)bg * S_ * D_ + tid]);
  float s1 = c, s2 = c * c;
#pragma unroll
  for (int off = 32; off > 0; off >>= 1) {
    s1 += __shfl_down(s1, off, 64);
    s2 += __shfl_down(s2, off, 64);
  }
  __shared__ float ws1[4], ws2[4], stats[2];
  __shared__ float lnD[256], lnA[256];
  int wid = tid >> 6, lane = tid & 63;
  if (lane == 0) { ws1[wid] = s1; ws2[wid] = s2; }
  __syncthreads();
  if (tid == 0) {
    float t1 = ws1[0] + ws1[1] + ws1[2] + ws1[3];
    float t2 = ws2[0] + ws2[1] + ws2[2] + ws2[3];
    float mean = t1 * (1.f / 256.f);
    float var = t2 * (1.f / 256.f) - mean * mean;
    stats[0] = mean;
    stats[1] = rsqrtf(var + 1e-5f);
  }
  __syncthreads();
  float n = (c - stats[0]) * stats[1];
  lnD[tid] = n * ldf(dg, tid, f) + ldf(dbt, tid, f);
  lnA[tid] = n * ldf(ag, tid, f) + ldf(abt, tid, f);
  __syncthreads();
  if (tid < NC_) {
    float acc = ldf(dbias, tid, f);
    for (int k = 0; k < D_; k++) acc += lnD[k] * ldf(dW, k * NC_ + tid, f);
    if (f) ((float*)out)[bg * NC_ + tid] = acc;
    else   ((bf16*)out)[bg * NC_ + tid] = __float2bfloat16(acc);
  } else if (tid == 8) {
    float acc = ldf(abias, 0, f);
    for (int k = 0; k < D_; k++) acc += lnA[k] * ldf(aW, k, f);
    if (f) ((float*)out)[B_ * NC_ + bg] = acc;
    else   ((bf16*)out)[B_ * NC_ + bg] = __float2bfloat16(acc);
  }
}

// ---------------------------------------------------------------------------
extern "C" void kernel_launch(void* const* d_in, const int* in_sizes, int n_in,
                              void* d_out, int out_size, void* d_ws, size_t ws_size,
                              hipStream_t stream)
{
  (void)in_sizes; (void)out_size; (void)d_ws; (void)ws_size;
  if (n_in < 34) return;
  const int* token_types  = (const int*)d_in[0];
  const int* decision_ids = (const int*)d_in[1];

  probe_kernel<<<1, 256, 0, stream>>>(d_in[12]);   // pos_embed

  wtrans_kernel<<<(DEPTH_ * D_ * 768 + 255) / 256, 256, 0, stream>>>(
      d_in[14], QKVT_OFF, D_, 768, DEPTH_ * D_ * 768);
  wtrans_kernel<<<(DEPTH_ * D_ * D_ + 255) / 256, 256, 0, stream>>>(
      d_in[16], OUTT_OFF, D_, D_, DEPTH_ * D_ * D_);
  wtrans_kernel<<<(DEPTH_ * D_ * FF_ + 255) / 256, 256, 0, stream>>>(
      d_in[22], FFN1T_OFF, D_, FF_, DEPTH_ * D_ * FF_);
  wtrans_kernel<<<(DEPTH_ * FF_ * D_ + 255) / 256, 256, 0, stream>>>(
      d_in[24], FFN2T_OFF, FF_, D_, DEPTH_ * FF_ * D_);

  embed_kernel<<<MTOT, 256, 0, stream>>>(token_types, decision_ids,
      d_in[2], d_in[3], d_in[4], d_in[5], d_in[6], d_in[7], d_in[8],
      d_in[9], d_in[10], d_in[11], d_in[12], d_in[13]);

  for (int i = 0; i < DEPTH_; i++) {
    gemm_mfma<<<6 * MT128, 256, 0, stream>>>(XOFF,
        QKVT_OFF + i * D_ * 768, d_in[15], (size_t)i * 768, C1OFF, 768, D_, 0, 6);
    attn_kernel<<<B_ * H_, 320, 0, stream>>>();
    gemm_mfma<<<2 * MT128, 256, 0, stream>>>(C2OFF,
        OUTT_OFF + i * D_ * D_, d_in[17], (size_t)i * D_, C1OFF, D_, D_, 0, 2);   // y1 -> c1
    resln_kernel<<<MTOT / 4, 256, 0, stream>>>(C1OFF,
        d_in[18], (size_t)i * D_, d_in[19], (size_t)i * D_);
    ffn_fused<<<MT64, 256, 0, stream>>>(
        FFN1T_OFF + i * D_ * FF_, FFN2T_OFF + i * FF_ * D_,
        d_in[23], (size_t)i * FF_, d_in[25], (size_t)i * D_,
        d_in[20], d_in[21], (size_t)i * D_);
  }
  head_kernel<<<B_, 256, 0, stream>>>(d_in[26], d_in[27], d_in[28], d_in[29],
      d_in[30], d_in[31], d_in[32], d_in[33], d_out);
}

// Round 13
// 2871.873 us; speedup vs baseline: 1.0988x; 1.0988x over previous
//
#include <hip/hip_runtime.h>
#include <hip/hip_bf16.h>

typedef __hip_bfloat16 bf16;
typedef unsigned short u16;
typedef __attribute__((ext_vector_type(8))) short s16x8;   // 8 bf16 (4 VGPRs) MFMA frag
typedef __attribute__((ext_vector_type(4))) float f32x4;   // MFMA accumulator

#define B_ 512
#define T_ 150
#define S_ 151
#define D_ 256
#define H_ 8
#define HD_ 32
#define FF_ 1024
#define NC_ 4
#define DEPTH_ 6
#define MTOT 77312            // B_*S_ = 128 * 604 = 64 * 1208
#define MT128 (MTOT / 128)    // 604
#define MT64 (MTOT / 64)      // 1208

// bf16 workspace regions (elements):
#define XOFF 0
#define C1OFF (MTOT * D_)               // x: MTOT*256
#define C2OFF (C1OFF + MTOT * FF_)      // c1: MTOT*1024 (qkv / ffn1 out)
#define WSELEMS (C2OFF + MTOT * D_)     // c2: MTOT*256 (attn out)

// Transposed bf16 weights Wt[N][K], all layers, rebuilt per call:
#define QKVT_OFF 0
#define OUTT_OFF (QKVT_OFF + DEPTH_ * D_ * 768)
#define FFN1T_OFF (OUTT_OFF + DEPTH_ * D_ * D_)
#define FFN2T_OFF (FFN1T_OFF + DEPTH_ * D_ * FF_)
#define WTELEMS (FFN2T_OFF + DEPTH_ * FF_ * D_)    // 9.4 MB

// Static device memory (d_ws proved unusable rounds 1-3).
__device__ __align__(16) u16 g_ws[WSELEMS];
__device__ __align__(16) u16 g_wt[WTELEMS];
__device__ int g_f32flag;   // 1 => external buffers f32, 0 => bf16

__device__ __forceinline__ float ldf(const void* p, size_t i, int f) {
  return f ? ((const float*)p)[i] : __bfloat162float(((const bf16*)p)[i]);
}
__device__ __forceinline__ float b2f(u16 u) {
  union { unsigned int i; float f; } v; v.i = ((unsigned int)u) << 16; return v.f;
}
__device__ __forceinline__ u16 f2b(float x) {
  bf16 h = __float2bfloat16(x);
  return *reinterpret_cast<u16*>(&h);
}

// Async global->LDS, 16 B/lane. LDS dest = wave-uniform base + lane*16.
typedef __attribute__((address_space(3))) void lds_void;
typedef const __attribute__((address_space(1))) void glob_void;
__device__ __forceinline__ void gload_lds16(const u16* g, u16* l) {
  __builtin_amdgcn_global_load_lds((glob_void*)g, (lds_void*)l, 16, 0, 0);
}

// ---------------------------------------------------------------------------
// Dtype probe on pos_embed (38656 elems ~N(0,0.02^2)) viewed as 16-bit words.
// ---------------------------------------------------------------------------
#define PROBE_N 38656
__global__ __launch_bounds__(256) void probe_kernel(const void* pe)
{
  const u16* w = (const u16*)pe;
  int susp = 0, zeroEven = 0;
  for (int k = threadIdx.x; k < PROBE_N; k += 256) {
    u16 u = w[k];
    int ex = (u >> 7) & 0xFF;
    if (ex >= 141) susp++;
    if ((k & 1) == 0 && (u & 0x7FFF) == 0) zeroEven++;
  }
  __shared__ int s_susp, s_zero;
  if (threadIdx.x == 0) { s_susp = 0; s_zero = 0; }
  __syncthreads();
  atomicAdd(&s_susp, susp);
  atomicAdd(&s_zero, zeroEven);
  __syncthreads();
  if (threadIdx.x == 0)
    g_f32flag = (s_susp > 0 || s_zero >= ((PROBE_N / 2) * 9) / 10) ? 1 : 0;
}

// ---------------------------------------------------------------------------
// Weight transpose+convert: Wt[l][n][k] = W[l][k][n] as bf16.
// ---------------------------------------------------------------------------
__global__ __launch_bounds__(256) void wtrans_kernel(const void* src, int dstOff,
                                                     int K, int N, int total)
{
  const int f = g_f32flag;
  int idx = blockIdx.x * 256 + threadIdx.x;
  if (idx >= total) return;
  int kn = K * N;
  int l = idx / kn;
  int r = idx - l * kn;
  int k = r / N;
  int n = r - k * N;
  g_wt[dstOff + (size_t)l * kn + (size_t)n * K + k] = f2b(ldf(src, idx, f));
}

// ---------------------------------------------------------------------------
// Embedding: row = blockIdx.x, writes bf16 x.
// ---------------------------------------------------------------------------
__global__ __launch_bounds__(256) void embed_kernel(
    const int* __restrict__ tt, const int* __restrict__ dids,
    const void* av, const void* dv, const void* vv,
    const void* aW, const void* ab, const void* dW, const void* db,
    const void* vW, const void* vb, const void* table, const void* pos,
    const void* cls)
{
  const int f = g_f32flag;
  u16* x = g_ws + XOFF;
  int row = blockIdx.x;
  int d = threadIdx.x;
  int b = row / S_;
  int s = row - b * S_;
  float val;
  if (s == 0) {
    val = ldf(cls, d, f);
  } else {
    int t = s - 1;
    int idx = b * T_ + t;
    int ty = tt[idx];
    if (ty == 0) {
      val = ldf(av, idx, f) * ldf(aW, d, f) + ldf(ab, d, f);
    } else if (ty == 1) {
      float acc = ldf(db, d, f) + ldf(vb, d, f);
#pragma unroll
      for (int i = 0; i < 10; i++) acc += ldf(dv, (size_t)idx * 10 + i, f) * ldf(dW, i * D_ + d, f);
#pragma unroll
      for (int i = 0; i < 3; i++) acc += ldf(vv, (size_t)idx * 3 + i, f) * ldf(vW, i * D_ + d, f);
      val = acc;
    } else if (ty == 2) {
      int did = dids[idx] & (NC_ - 1);
      val = ldf(table, (size_t)did * D_ + d, f);
    } else {
      val = 0.f;
    }
  }
  val += ldf(pos, s * D_ + d, f);
  x[(size_t)row * D_ + d] = f2b(val);
}

// ---------------------------------------------------------------------------
// MFMA GEMM (round-9 proven): 128x128, BK=64, 256 thr, global_load_lds w=16,
// xor-swizzled chunks (0 conflicts), XCD swizzle, LDS-staged epilogue.
// Used for qkv (N=768) and ffn1 (N=1024, relu).
// ---------------------------------------------------------------------------
__global__ __launch_bounds__(256) void gemm_mfma(
    int aOff, int wtOff, const void* bias, size_t bOff,
    int cOff, int N, int K, int relu, int NB)
{
  const int f = g_f32flag;
  const u16* A = g_ws + aOff;
  const u16* Bt = g_wt + wtOff;
  u16* C = g_ws + cOff;
  __shared__ __align__(16) u16 sm[16384];
  const int tid = threadIdx.x;

  int gblk = blockIdx.x;
  int bm, bn;
  {
    const int full = (MT128 / 8) * 8;        // 600
    if (gblk < NB * full) {
      int per = NB * 8;
      int grp = gblk / per, rem = gblk % per;
      bm = grp * 8 + (rem & 7);
      bn = rem >> 3;
    } else {
      int id = gblk - NB * full;
      bm = full + id / NB;
      bn = id % NB;
    }
  }

  const int lane = tid & 63, wid = tid >> 6;
  const int wm = (wid >> 1) * 64, wn = (wid & 1) * 64;
  const int frow = lane & 15, quad = lane >> 4;

  const int rg = lane >> 3;
  const int ck = ((lane & 7) ^ rg) * 8;
  const u16* Ag[4]; const u16* Bg[4];
  u16 *Asl[4], *Bsl[4];
#pragma unroll
  for (int p = 0; p < 4; p++) {
    int grp = wid * 4 + p;
    int row = grp * 8 + rg;
    Ag[p] = A + (size_t)(bm * 128 + row) * K + ck;
    Bg[p] = Bt + (size_t)(bn * 128 + row) * K + ck;
    Asl[p] = &sm[grp * 512];
    Bsl[p] = &sm[8192 + grp * 512];
  }

  f32x4 acc[4][4] = {};

  for (int kt = 0; kt < K; kt += 64) {
    if (kt) __syncthreads();
#pragma unroll
    for (int p = 0; p < 4; p++) {
      gload_lds16(Ag[p] + kt, Asl[p]);
      gload_lds16(Bg[p] + kt, Bsl[p]);
    }
    __syncthreads();
#pragma unroll
    for (int s = 0; s < 2; s++) {
      s16x8 af[4], bfr[4];
      const int cfr = ((s * 4 + quad) ^ (frow & 7)) * 8;
#pragma unroll
      for (int t = 0; t < 4; t++) {
        af[t]  = *(const s16x8*)&sm[(wm + t * 16 + frow) * 64 + cfr];
        bfr[t] = *(const s16x8*)&sm[8192 + (wn + t * 16 + frow) * 64 + cfr];
      }
#pragma unroll
      for (int mt = 0; mt < 4; mt++)
#pragma unroll
        for (int nt = 0; nt < 4; nt++)
          acc[mt][nt] = __builtin_amdgcn_mfma_f32_16x16x32_bf16(af[mt], bfr[nt], acc[mt][nt], 0, 0, 0);
    }
  }

  float bv[4];
#pragma unroll
  for (int nt = 0; nt < 4; nt++)
    bv[nt] = ldf(bias, bOff + (size_t)(bn * 128 + wn + nt * 16 + frow), f);
  __syncthreads();
#pragma unroll
  for (int p = 0; p < 2; p++) {
    if ((wid >> 1) == p) {
#pragma unroll
      for (int mt = 0; mt < 4; mt++)
#pragma unroll
        for (int nt = 0; nt < 4; nt++)
#pragma unroll
          for (int r = 0; r < 4; r++) {
            int rl = (wm & 63) + mt * 16 + quad * 4 + r;
            float v = acc[mt][nt][r] + bv[nt];
            if (relu) v = fmaxf(v, 0.f);
            sm[rl * 136 + wn + nt * 16 + frow] = f2b(v);
          }
    }
    __syncthreads();
    {
      int rl = tid >> 2;
      int cq = (tid & 3) * 32;
      size_t gb = (size_t)(bm * 128 + p * 64 + rl) * N + bn * 128 + cq;
#pragma unroll
      for (int j = 0; j < 4; j++)
        *(s16x8*)(C + gb + j * 8) = *(const s16x8*)&sm[rl * 136 + cq + j * 8];
    }
    __syncthreads();
  }
}

// ---------------------------------------------------------------------------
// Fused-LN GEMM: x = LN(x + A@W + bias) * g + b. 64x256 tile (full 256-wide
// output row in one block), 256 thr = 4 waves side-by-side in N, each wave a
// 64x64 quadrant. Single-phase K-loop identical to gemm_mfma (no extra
// barriers — the round-12 lesson). LDS 40KB -> 4 blocks/CU. Epilogue:
// y -> LDS 64x264, then per-row residual+LN (4 lanes/row, shfl_xor reduce;
// pattern numerically verified in round 12). Replaces out-proj+resln1 and
// ffn2+resln2: kills 2 launches + ~158 MB/layer of y write+read traffic.
// ---------------------------------------------------------------------------
__global__ __launch_bounds__(256) void gemm_ln(
    int aOff, int wtOff, const void* bias, size_t bOff,
    const void* lng, const void* lnb, size_t lnOff, int K)
{
  const int f = g_f32flag;
  const u16* A = g_ws + aOff;
  const u16* Bt = g_wt + wtOff;
  __shared__ __align__(16) u16 sm[20480];   // A 8KB | B 32KB; epilogue 64x264
  const int tid = threadIdx.x;
  const int bm = blockIdx.x;                // 64-row tile
  const int lane = tid & 63, wid = tid >> 6;
  const int wn = wid * 64;
  const int frow = lane & 15, quad = lane >> 4;
  const int rg = lane >> 3;
  const int ck = ((lane & 7) ^ rg) * 8;

  const u16* Ag[2]; u16* Asl[2];
  const u16* Bg[8]; u16* Bsl[8];
#pragma unroll
  for (int p = 0; p < 2; p++) {
    int grp = wid * 2 + p;                  // 0..8: rows 0..63
    Ag[p] = A + (size_t)(bm * 64 + grp * 8 + rg) * K + ck;
    Asl[p] = &sm[grp * 512];
  }
#pragma unroll
  for (int p = 0; p < 8; p++) {
    int grp = wid * 8 + p;                  // 0..32: Wt rows 0..255
    Bg[p] = Bt + (size_t)(grp * 8 + rg) * K + ck;
    Bsl[p] = &sm[4096 + grp * 512];
  }

  f32x4 acc[4][4] = {};

  for (int kt = 0; kt < K; kt += 64) {
    if (kt) __syncthreads();
#pragma unroll
    for (int p = 0; p < 2; p++) gload_lds16(Ag[p] + kt, Asl[p]);
#pragma unroll
    for (int p = 0; p < 8; p++) gload_lds16(Bg[p] + kt, Bsl[p]);
    __syncthreads();
#pragma unroll
    for (int s = 0; s < 2; s++) {
      s16x8 af[4], bfr[4];
      const int cfr = ((s * 4 + quad) ^ (frow & 7)) * 8;
#pragma unroll
      for (int t = 0; t < 4; t++) {
        af[t]  = *(const s16x8*)&sm[(t * 16 + frow) * 64 + cfr];
        bfr[t] = *(const s16x8*)&sm[4096 + (wn + t * 16 + frow) * 64 + cfr];
      }
#pragma unroll
      for (int mt = 0; mt < 4; mt++)
#pragma unroll
        for (int nt = 0; nt < 4; nt++)
          acc[mt][nt] = __builtin_amdgcn_mfma_f32_16x16x32_bf16(af[mt], bfr[nt], acc[mt][nt], 0, 0, 0);
    }
  }

  float bv[4];
#pragma unroll
  for (int nt = 0; nt < 4; nt++)
    bv[nt] = ldf(bias, bOff + (size_t)(wn + nt * 16 + frow), f);
  __syncthreads();   // all frag reads done; reuse sm as y-buf 64x264
#pragma unroll
  for (int mt = 0; mt < 4; mt++)
#pragma unroll
    for (int nt = 0; nt < 4; nt++)
#pragma unroll
      for (int r = 0; r < 4; r++) {
        int row = mt * 16 + quad * 4 + r;
        int col = wn + nt * 16 + frow;
        sm[row * 264 + col] = f2b(acc[mt][nt][r] + bv[nt]);
      }
  __syncthreads();
  {
    int rl = tid >> 2;                 // row 0..63 (4 lanes per row)
    int cq = (tid & 3) * 64;           // 64 cols per lane
    size_t rowg = (size_t)bm * 64 + rl;
    float s1 = 0.f, s2 = 0.f;
#pragma unroll
    for (int j = 0; j < 8; j++) {
      s16x8 yv = *(const s16x8*)&sm[rl * 264 + cq + j * 8];
      s16x8 xv = *(const s16x8*)(g_ws + XOFF + rowg * 256 + cq + j * 8);
#pragma unroll
      for (int e = 0; e < 8; e++) {
        float v = b2f((u16)yv[e]) + b2f((u16)xv[e]);
        s1 += v; s2 += v * v;
      }
    }
    s1 += __shfl_xor(s1, 1, 64); s2 += __shfl_xor(s2, 1, 64);
    s1 += __shfl_xor(s1, 2, 64); s2 += __shfl_xor(s2, 2, 64);
    float mean = s1 * (1.f / 256.f);
    float var = s2 * (1.f / 256.f) - mean * mean;
    float rs = rsqrtf(var + 1e-5f);
#pragma unroll
    for (int j = 0; j < 8; j++) {
      s16x8 yv = *(const s16x8*)&sm[rl * 264 + cq + j * 8];
      s16x8 xv = *(const s16x8*)(g_ws + XOFF + rowg * 256 + cq + j * 8);
      s16x8 ov;
#pragma unroll
      for (int e = 0; e < 8; e++) {
        float v = b2f((u16)yv[e]) + b2f((u16)xv[e]);
        int col = cq + j * 8 + e;
        ov[e] = (short)f2b((v - mean) * rs * ldf(lng, lnOff + col, f) + ldf(lnb, lnOff + col, f));
      }
      *(s16x8*)(g_ws + XOFF + rowg * 256 + cq + j * 8) = ov;
    }
  }
}

// ---------------------------------------------------------------------------
// MFMA attention (S=151 padded 160), VLD/PLD=170 (bank fix, round 11).
// ---------------------------------------------------------------------------
#define SP 160
#define KLD 40
#define VLD 170
#define PLD 170

__global__ __launch_bounds__(320) void attn_kernel()
{
  const u16* qkv = g_ws + C1OFF;
  u16* o = g_ws + C2OFF;
  __shared__ __align__(16) u16 Ks[SP * KLD];
  __shared__ __align__(16) u16 Vt[HD_ * VLD];
  __shared__ __align__(16) u16 Ps[5][16 * PLD];
  int bh = blockIdx.x;
  int b = bh >> 3, h = bh & 7;
  int tid = threadIdx.x;
  int lane = tid & 63, wid = tid >> 6;
  const u16* base = qkv + (size_t)b * S_ * 768;

  for (int g = tid; g < SP * 4; g += 320) {
    int j = g >> 2, d0 = (g & 3) * 8;
    s16x8 kv = {0, 0, 0, 0, 0, 0, 0, 0};
    if (j < S_) kv = *(const s16x8*)(base + (size_t)j * 768 + 256 + h * 32 + d0);
    *(s16x8*)&Ks[j * KLD + d0] = kv;
  }
  for (int g = tid; g < SP * 4; g += 320) {
    int j = g >> 2, d0 = (g & 3) * 8;
    s16x8 vv = {0, 0, 0, 0, 0, 0, 0, 0};
    if (j < S_) vv = *(const s16x8*)(base + (size_t)j * 768 + 512 + h * 32 + d0);
#pragma unroll
    for (int i = 0; i < 8; i++) Vt[(d0 + i) * VLD + j] = (u16)vv[i];
  }
  __syncthreads();

  const int frow = lane & 15;
  const int quad = lane >> 4;
  const int fk = quad * 8;
  const float scale = 0.17677669529663687f;  // 1/sqrt(32)

  for (int round = 0; round < 2; round++) {
    int mt = round * 5 + wid;
    int qrow = mt * 16 + frow;
    s16x8 aq = {0, 0, 0, 0, 0, 0, 0, 0};
    if (qrow < S_) aq = *(const s16x8*)(base + (size_t)qrow * 768 + h * 32 + fk);
    f32x4 sacc[10];
#pragma unroll
    for (int nt = 0; nt < 10; nt++) {
      s16x8 bk = *(const s16x8*)&Ks[(nt * 16 + frow) * KLD + fk];
      f32x4 z = {0.f, 0.f, 0.f, 0.f};
      sacc[nt] = __builtin_amdgcn_mfma_f32_16x16x32_bf16(aq, bk, z, 0, 0, 0);
    }
#pragma unroll
    for (int nt = 0; nt < 10; nt++) {
      int colg = nt * 16 + frow;
      float msk = (colg < S_) ? 1.f : 0.f;
#pragma unroll
      for (int r = 0; r < 4; r++)
        sacc[nt][r] = msk ? sacc[nt][r] * scale : -1e30f;
    }
    float inv[4];
#pragma unroll
    for (int r = 0; r < 4; r++) {
      float mx = -1e30f;
#pragma unroll
      for (int nt = 0; nt < 10; nt++) mx = fmaxf(mx, sacc[nt][r]);
#pragma unroll
      for (int m = 1; m < 16; m <<= 1) mx = fmaxf(mx, __shfl_xor(mx, m, 64));
      float sm2 = 0.f;
#pragma unroll
      for (int nt = 0; nt < 10; nt++) {
        float p = __expf(sacc[nt][r] - mx);
        sacc[nt][r] = p;
        sm2 += p;
      }
#pragma unroll
      for (int m = 1; m < 16; m <<= 1) sm2 += __shfl_xor(sm2, m, 64);
      inv[r] = 1.f / sm2;
    }
#pragma unroll
    for (int nt = 0; nt < 10; nt++)
#pragma unroll
      for (int r = 0; r < 4; r++)
        Ps[wid][(quad * 4 + r) * PLD + nt * 16 + frow] = f2b(sacc[nt][r]);
    f32x4 oacc[2] = {};
#pragma unroll
    for (int ks = 0; ks < 5; ks++) {
      s16x8 ap = *(const s16x8*)&Ps[wid][frow * PLD + ks * 32 + fk];
#pragma unroll
      for (int nt2 = 0; nt2 < 2; nt2++) {
        s16x8 bv = *(const s16x8*)&Vt[(nt2 * 16 + frow) * VLD + ks * 32 + fk];
        oacc[nt2] = __builtin_amdgcn_mfma_f32_16x16x32_bf16(ap, bv, oacc[nt2], 0, 0, 0);
      }
    }
#pragma unroll
    for (int nt2 = 0; nt2 < 2; nt2++)
#pragma unroll
      for (int r = 0; r < 4; r++) {
        int rowg = mt * 16 + quad * 4 + r;
        if (rowg < S_)
          o[(size_t)(b * S_ + rowg) * D_ + h * 32 + nt2 * 16 + frow] = f2b(oacc[nt2][r] * inv[r]);
      }
  }
}

// ---------------------------------------------------------------------------
// Head: cls row -> two LNs (shared stats) -> two tiny matvecs.
// ---------------------------------------------------------------------------
__global__ __launch_bounds__(256) void head_kernel(
    const void* dg, const void* dbt, const void* dW, const void* dbias,
    const void* ag, const void* abt, const void* aW, const void* abias,
    void* out)
{
  const int f = g_f32flag;
  const u16* x = g_ws + XOFF;
  int bg = blockIdx.x;
  int tid = threadIdx.x;
  float c = b2f(x[(size_t)bg * S_ * D_ + tid]);
  float s1 = c, s2 = c * c;
#pragma unroll
  for (int off = 32; off > 0; off >>= 1) {
    s1 += __shfl_down(s1, off, 64);
    s2 += __shfl_down(s2, off, 64);
  }
  __shared__ float ws1[4], ws2[4], stats[2];
  __shared__ float lnD[256], lnA[256];
  int wid = tid >> 6, lane = tid & 63;
  if (lane == 0) { ws1[wid] = s1; ws2[wid] = s2; }
  __syncthreads();
  if (tid == 0) {
    float t1 = ws1[0] + ws1[1] + ws1[2] + ws1[3];
    float t2 = ws2[0] + ws2[1] + ws2[2] + ws2[3];
    float mean = t1 * (1.f / 256.f);
    float var = t2 * (1.f / 256.f) - mean * mean;
    stats[0] = mean;
    stats[1] = rsqrtf(var + 1e-5f);
  }
  __syncthreads();
  float n = (c - stats[0]) * stats[1];
  lnD[tid] = n * ldf(dg, tid, f) + ldf(dbt, tid, f);
  lnA[tid] = n * ldf(ag, tid, f) + ldf(abt, tid, f);
  __syncthreads();
  if (tid < NC_) {
    float acc = ldf(dbias, tid, f);
    for (int k = 0; k < D_; k++) acc += lnD[k] * ldf(dW, k * NC_ + tid, f);
    if (f) ((float*)out)[bg * NC_ + tid] = acc;
    else   ((bf16*)out)[bg * NC_ + tid] = __float2bfloat16(acc);
  } else if (tid == 8) {
    float acc = ldf(abias, 0, f);
    for (int k = 0; k < D_; k++) acc += lnA[k] * ldf(aW, k, f);
    if (f) ((float*)out)[B_ * NC_ + bg] = acc;
    else   ((bf16*)out)[B_ * NC_ + bg] = __float2bfloat16(acc);
  }
}

// ---------------------------------------------------------------------------
extern "C" void kernel_launch(void* const* d_in, const int* in_sizes, int n_in,
                              void* d_out, int out_size, void* d_ws, size_t ws_size,
                              hipStream_t stream)
{
  (void)in_sizes; (void)out_size; (void)d_ws; (void)ws_size;
  if (n_in < 34) return;
  const int* token_types  = (const int*)d_in[0];
  const int* decision_ids = (const int*)d_in[1];

  probe_kernel<<<1, 256, 0, stream>>>(d_in[12]);   // pos_embed

  wtrans_kernel<<<(DEPTH_ * D_ * 768 + 255) / 256, 256, 0, stream>>>(
      d_in[14], QKVT_OFF, D_, 768, DEPTH_ * D_ * 768);
  wtrans_kernel<<<(DEPTH_ * D_ * D_ + 255) / 256, 256, 0, stream>>>(
      d_in[16], OUTT_OFF, D_, D_, DEPTH_ * D_ * D_);
  wtrans_kernel<<<(DEPTH_ * D_ * FF_ + 255) / 256, 256, 0, stream>>>(
      d_in[22], FFN1T_OFF, D_, FF_, DEPTH_ * D_ * FF_);
  wtrans_kernel<<<(DEPTH_ * FF_ * D_ + 255) / 256, 256, 0, stream>>>(
      d_in[24], FFN2T_OFF, FF_, D_, DEPTH_ * FF_ * D_);

  embed_kernel<<<MTOT, 256, 0, stream>>>(token_types, decision_ids,
      d_in[2], d_in[3], d_in[4], d_in[5], d_in[6], d_in[7], d_in[8],
      d_in[9], d_in[10], d_in[11], d_in[12], d_in[13]);

  for (int i = 0; i < DEPTH_; i++) {
    gemm_mfma<<<6 * MT128, 256, 0, stream>>>(XOFF,
        QKVT_OFF + i * D_ * 768, d_in[15], (size_t)i * 768, C1OFF, 768, D_, 0, 6);
    attn_kernel<<<B_ * H_, 320, 0, stream>>>();
    // out-proj fused: x = LN1(x + attn_out @ Wout + b)
    gemm_ln<<<MT64, 256, 0, stream>>>(C2OFF,
        OUTT_OFF + i * D_ * D_, d_in[17], (size_t)i * D_,
        d_in[18], d_in[19], (size_t)i * D_, D_);
    gemm_mfma<<<8 * MT128, 256, 0, stream>>>(XOFF,
        FFN1T_OFF + i * D_ * FF_, d_in[23], (size_t)i * FF_, C1OFF, FF_, D_, 1, 8);
    // ffn2 fused: x = LN2(x + ff @ W2 + b)
    gemm_ln<<<MT64, 256, 0, stream>>>(C1OFF,
        FFN2T_OFF + i * FF_ * D_, d_in[25], (size_t)i * D_,
        d_in[20], d_in[21], (size_t)i * D_, FF_);
  }
  head_kernel<<<B_, 256, 0, stream>>>(d_in[26], d_in[27], d_in[28], d_in[29],
      d_in[30], d_in[31], d_in[32], d_in[33], d_out);
}

// Round 14
// 2638.678 us; speedup vs baseline: 1.1959x; 1.0884x over previous
//
#include <hip/hip_runtime.h>
#include <hip/hip_bf16.h>

typedef __hip_bfloat16 bf16;
typedef unsigned short u16;
typedef __attribute__((ext_vector_type(8))) short s16x8;   // 8 bf16 (4 VGPRs) MFMA frag
typedef __attribute__((ext_vector_type(4))) float f32x4;   // MFMA accumulator

#define B_ 512
#define T_ 150
#define S_ 151
#define D_ 256
#define H_ 8
#define HD_ 32
#define FF_ 1024
#define NC_ 4
#define DEPTH_ 6
#define MTOT 77312            // B_*S_ = 128 * 604 = 64 * 1208
#define MT128 (MTOT / 128)    // 604
#define MT64 (MTOT / 64)      // 1208

// bf16 workspace regions (elements):
#define XOFF 0
#define C1OFF (MTOT * D_)               // x: MTOT*256
#define C2OFF (C1OFF + MTOT * FF_)      // c1: MTOT*1024 (qkv / ffn1 out)
#define WSELEMS (C2OFF + MTOT * D_)     // c2: MTOT*256 (attn out)

// Transposed bf16 weights Wt[N][K], all layers, rebuilt per call:
#define QKVT_OFF 0
#define OUTT_OFF (QKVT_OFF + DEPTH_ * D_ * 768)
#define FFN1T_OFF (OUTT_OFF + DEPTH_ * D_ * D_)
#define FFN2T_OFF (FFN1T_OFF + DEPTH_ * D_ * FF_)
#define WTELEMS (FFN2T_OFF + DEPTH_ * FF_ * D_)    // 9.4 MB

// Static device memory (d_ws proved unusable rounds 1-3).
__device__ __align__(16) u16 g_ws[WSELEMS];
__device__ __align__(16) u16 g_wt[WTELEMS];
__device__ int g_f32flag;   // 1 => external buffers f32, 0 => bf16

__device__ __forceinline__ float ldf(const void* p, size_t i, int f) {
  return f ? ((const float*)p)[i] : __bfloat162float(((const bf16*)p)[i]);
}
__device__ __forceinline__ float b2f(u16 u) {
  union { unsigned int i; float f; } v; v.i = ((unsigned int)u) << 16; return v.f;
}
__device__ __forceinline__ u16 f2b(float x) {
  bf16 h = __float2bfloat16(x);
  return *reinterpret_cast<u16*>(&h);
}

// Async global->LDS, 16 B/lane. LDS dest = wave-uniform base + lane*16.
typedef __attribute__((address_space(3))) void lds_void;
typedef const __attribute__((address_space(1))) void glob_void;
__device__ __forceinline__ void gload_lds16(const u16* g, u16* l) {
  __builtin_amdgcn_global_load_lds((glob_void*)g, (lds_void*)l, 16, 0, 0);
}

// ---------------------------------------------------------------------------
// Dtype probe on pos_embed (38656 elems ~N(0,0.02^2)) viewed as 16-bit words.
// ---------------------------------------------------------------------------
#define PROBE_N 38656
__global__ __launch_bounds__(256) void probe_kernel(const void* pe)
{
  const u16* w = (const u16*)pe;
  int susp = 0, zeroEven = 0;
  for (int k = threadIdx.x; k < PROBE_N; k += 256) {
    u16 u = w[k];
    int ex = (u >> 7) & 0xFF;
    if (ex >= 141) susp++;
    if ((k & 1) == 0 && (u & 0x7FFF) == 0) zeroEven++;
  }
  __shared__ int s_susp, s_zero;
  if (threadIdx.x == 0) { s_susp = 0; s_zero = 0; }
  __syncthreads();
  atomicAdd(&s_susp, susp);
  atomicAdd(&s_zero, zeroEven);
  __syncthreads();
  if (threadIdx.x == 0)
    g_f32flag = (s_susp > 0 || s_zero >= ((PROBE_N / 2) * 9) / 10) ? 1 : 0;
}

// ---------------------------------------------------------------------------
// Weight transpose+convert: Wt[l][n][k] = W[l][k][n] as bf16.
// ---------------------------------------------------------------------------
__global__ __launch_bounds__(256) void wtrans_kernel(const void* src, int dstOff,
                                                     int K, int N, int total)
{
  const int f = g_f32flag;
  int idx = blockIdx.x * 256 + threadIdx.x;
  if (idx >= total) return;
  int kn = K * N;
  int l = idx / kn;
  int r = idx - l * kn;
  int k = r / N;
  int n = r - k * N;
  g_wt[dstOff + (size_t)l * kn + (size_t)n * K + k] = f2b(ldf(src, idx, f));
}

// ---------------------------------------------------------------------------
// Embedding: row = blockIdx.x, writes bf16 x.
// ---------------------------------------------------------------------------
__global__ __launch_bounds__(256) void embed_kernel(
    const int* __restrict__ tt, const int* __restrict__ dids,
    const void* av, const void* dv, const void* vv,
    const void* aW, const void* ab, const void* dW, const void* db,
    const void* vW, const void* vb, const void* table, const void* pos,
    const void* cls)
{
  const int f = g_f32flag;
  u16* x = g_ws + XOFF;
  int row = blockIdx.x;
  int d = threadIdx.x;
  int b = row / S_;
  int s = row - b * S_;
  float val;
  if (s == 0) {
    val = ldf(cls, d, f);
  } else {
    int t = s - 1;
    int idx = b * T_ + t;
    int ty = tt[idx];
    if (ty == 0) {
      val = ldf(av, idx, f) * ldf(aW, d, f) + ldf(ab, d, f);
    } else if (ty == 1) {
      float acc = ldf(db, d, f) + ldf(vb, d, f);
#pragma unroll
      for (int i = 0; i < 10; i++) acc += ldf(dv, (size_t)idx * 10 + i, f) * ldf(dW, i * D_ + d, f);
#pragma unroll
      for (int i = 0; i < 3; i++) acc += ldf(vv, (size_t)idx * 3 + i, f) * ldf(vW, i * D_ + d, f);
      val = acc;
    } else if (ty == 2) {
      int did = dids[idx] & (NC_ - 1);
      val = ldf(table, (size_t)did * D_ + d, f);
    } else {
      val = 0.f;
    }
  }
  val += ldf(pos, s * D_ + d, f);
  x[(size_t)row * D_ + d] = f2b(val);
}

// ---------------------------------------------------------------------------
// MFMA GEMM (round-9 proven): 128x128, BK=64, 256 thr, global_load_lds w=16,
// xor-swizzled chunks (0 conflicts), XCD swizzle, LDS-staged epilogue.
// __launch_bounds__(256,3): round-13 counters showed 112 VGPR + 64 AGPR =
// 176 unified -> only 2 blocks/CU; capping at 170 buys a 3rd resident block.
// ---------------------------------------------------------------------------
__global__ __launch_bounds__(256, 3) void gemm_mfma(
    int aOff, int wtOff, const void* bias, size_t bOff,
    int cOff, int N, int K, int relu, int NB)
{
  const int f = g_f32flag;
  const u16* A = g_ws + aOff;
  const u16* Bt = g_wt + wtOff;
  u16* C = g_ws + cOff;
  __shared__ __align__(16) u16 sm[16384];
  const int tid = threadIdx.x;

  int gblk = blockIdx.x;
  int bm, bn;
  {
    const int full = (MT128 / 8) * 8;        // 600
    if (gblk < NB * full) {
      int per = NB * 8;
      int grp = gblk / per, rem = gblk % per;
      bm = grp * 8 + (rem & 7);
      bn = rem >> 3;
    } else {
      int id = gblk - NB * full;
      bm = full + id / NB;
      bn = id % NB;
    }
  }

  const int lane = tid & 63, wid = tid >> 6;
  const int wm = (wid >> 1) * 64, wn = (wid & 1) * 64;
  const int frow = lane & 15, quad = lane >> 4;

  const int rg = lane >> 3;
  const int ck = ((lane & 7) ^ rg) * 8;
  const u16* Ag[4]; const u16* Bg[4];
  u16 *Asl[4], *Bsl[4];
#pragma unroll
  for (int p = 0; p < 4; p++) {
    int grp = wid * 4 + p;
    int row = grp * 8 + rg;
    Ag[p] = A + (size_t)(bm * 128 + row) * K + ck;
    Bg[p] = Bt + (size_t)(bn * 128 + row) * K + ck;
    Asl[p] = &sm[grp * 512];
    Bsl[p] = &sm[8192 + grp * 512];
  }

  f32x4 acc[4][4] = {};

  for (int kt = 0; kt < K; kt += 64) {
    if (kt) __syncthreads();
#pragma unroll
    for (int p = 0; p < 4; p++) {
      gload_lds16(Ag[p] + kt, Asl[p]);
      gload_lds16(Bg[p] + kt, Bsl[p]);
    }
    __syncthreads();
#pragma unroll
    for (int s = 0; s < 2; s++) {
      s16x8 af[4], bfr[4];
      const int cfr = ((s * 4 + quad) ^ (frow & 7)) * 8;
#pragma unroll
      for (int t = 0; t < 4; t++) {
        af[t]  = *(const s16x8*)&sm[(wm + t * 16 + frow) * 64 + cfr];
        bfr[t] = *(const s16x8*)&sm[8192 + (wn + t * 16 + frow) * 64 + cfr];
      }
#pragma unroll
      for (int mt = 0; mt < 4; mt++)
#pragma unroll
        for (int nt = 0; nt < 4; nt++)
          acc[mt][nt] = __builtin_amdgcn_mfma_f32_16x16x32_bf16(af[mt], bfr[nt], acc[mt][nt], 0, 0, 0);
    }
  }

  float bv[4];
#pragma unroll
  for (int nt = 0; nt < 4; nt++)
    bv[nt] = ldf(bias, bOff + (size_t)(bn * 128 + wn + nt * 16 + frow), f);
  __syncthreads();
#pragma unroll
  for (int p = 0; p < 2; p++) {
    if ((wid >> 1) == p) {
#pragma unroll
      for (int mt = 0; mt < 4; mt++)
#pragma unroll
        for (int nt = 0; nt < 4; nt++)
#pragma unroll
          for (int r = 0; r < 4; r++) {
            int rl = (wm & 63) + mt * 16 + quad * 4 + r;
            float v = acc[mt][nt][r] + bv[nt];
            if (relu) v = fmaxf(v, 0.f);
            sm[rl * 136 + wn + nt * 16 + frow] = f2b(v);
          }
    }
    __syncthreads();
    {
      int rl = tid >> 2;
      int cq = (tid & 3) * 32;
      size_t gb = (size_t)(bm * 128 + p * 64 + rl) * N + bn * 128 + cq;
#pragma unroll
      for (int j = 0; j < 4; j++)
        *(s16x8*)(C + gb + j * 8) = *(const s16x8*)&sm[rl * 136 + cq + j * 8];
    }
    __syncthreads();
  }
}

// ---------------------------------------------------------------------------
// Fused-LN GEMM: x = LN(x + A@W + bias) * g + b. 64x256 tile, 256 thr =
// 4 waves side-by-side in N. Single-phase K-loop (round-12 lesson: no extra
// barriers). __launch_bounds__(256,3) for the same register-cliff reason.
// ---------------------------------------------------------------------------
__global__ __launch_bounds__(256, 3) void gemm_ln(
    int aOff, int wtOff, const void* bias, size_t bOff,
    const void* lng, const void* lnb, size_t lnOff, int K)
{
  const int f = g_f32flag;
  const u16* A = g_ws + aOff;
  const u16* Bt = g_wt + wtOff;
  __shared__ __align__(16) u16 sm[20480];   // A 8KB | B 32KB; epilogue 64x264
  const int tid = threadIdx.x;
  const int bm = blockIdx.x;                // 64-row tile
  const int lane = tid & 63, wid = tid >> 6;
  const int wn = wid * 64;
  const int frow = lane & 15, quad = lane >> 4;
  const int rg = lane >> 3;
  const int ck = ((lane & 7) ^ rg) * 8;

  const u16* Ag[2]; u16* Asl[2];
  const u16* Bg[8]; u16* Bsl[8];
#pragma unroll
  for (int p = 0; p < 2; p++) {
    int grp = wid * 2 + p;                  // 0..8: rows 0..63
    Ag[p] = A + (size_t)(bm * 64 + grp * 8 + rg) * K + ck;
    Asl[p] = &sm[grp * 512];
  }
#pragma unroll
  for (int p = 0; p < 8; p++) {
    int grp = wid * 8 + p;                  // 0..32: Wt rows 0..255
    Bg[p] = Bt + (size_t)(grp * 8 + rg) * K + ck;
    Bsl[p] = &sm[4096 + grp * 512];
  }

  f32x4 acc[4][4] = {};

  for (int kt = 0; kt < K; kt += 64) {
    if (kt) __syncthreads();
#pragma unroll
    for (int p = 0; p < 2; p++) gload_lds16(Ag[p] + kt, Asl[p]);
#pragma unroll
    for (int p = 0; p < 8; p++) gload_lds16(Bg[p] + kt, Bsl[p]);
    __syncthreads();
#pragma unroll
    for (int s = 0; s < 2; s++) {
      s16x8 af[4], bfr[4];
      const int cfr = ((s * 4 + quad) ^ (frow & 7)) * 8;
#pragma unroll
      for (int t = 0; t < 4; t++) {
        af[t]  = *(const s16x8*)&sm[(t * 16 + frow) * 64 + cfr];
        bfr[t] = *(const s16x8*)&sm[4096 + (wn + t * 16 + frow) * 64 + cfr];
      }
#pragma unroll
      for (int mt = 0; mt < 4; mt++)
#pragma unroll
        for (int nt = 0; nt < 4; nt++)
          acc[mt][nt] = __builtin_amdgcn_mfma_f32_16x16x32_bf16(af[mt], bfr[nt], acc[mt][nt], 0, 0, 0);
    }
  }

  float bv[4];
#pragma unroll
  for (int nt = 0; nt < 4; nt++)
    bv[nt] = ldf(bias, bOff + (size_t)(wn + nt * 16 + frow), f);
  __syncthreads();   // all frag reads done; reuse sm as y-buf 64x264
#pragma unroll
  for (int mt = 0; mt < 4; mt++)
#pragma unroll
    for (int nt = 0; nt < 4; nt++)
#pragma unroll
      for (int r = 0; r < 4; r++) {
        int row = mt * 16 + quad * 4 + r;
        int col = wn + nt * 16 + frow;
        sm[row * 264 + col] = f2b(acc[mt][nt][r] + bv[nt]);
      }
  __syncthreads();
  {
    int rl = tid >> 2;                 // row 0..63 (4 lanes per row)
    int cq = (tid & 3) * 64;           // 64 cols per lane
    size_t rowg = (size_t)bm * 64 + rl;
    float s1 = 0.f, s2 = 0.f;
#pragma unroll
    for (int j = 0; j < 8; j++) {
      s16x8 yv = *(const s16x8*)&sm[rl * 264 + cq + j * 8];
      s16x8 xv = *(const s16x8*)(g_ws + XOFF + rowg * 256 + cq + j * 8);
#pragma unroll
      for (int e = 0; e < 8; e++) {
        float v = b2f((u16)yv[e]) + b2f((u16)xv[e]);
        s1 += v; s2 += v * v;
      }
    }
    s1 += __shfl_xor(s1, 1, 64); s2 += __shfl_xor(s2, 1, 64);
    s1 += __shfl_xor(s1, 2, 64); s2 += __shfl_xor(s2, 2, 64);
    float mean = s1 * (1.f / 256.f);
    float var = s2 * (1.f / 256.f) - mean * mean;
    float rs = rsqrtf(var + 1e-5f);
#pragma unroll
    for (int j = 0; j < 8; j++) {
      s16x8 yv = *(const s16x8*)&sm[rl * 264 + cq + j * 8];
      s16x8 xv = *(const s16x8*)(g_ws + XOFF + rowg * 256 + cq + j * 8);
      s16x8 ov;
#pragma unroll
      for (int e = 0; e < 8; e++) {
        float v = b2f((u16)yv[e]) + b2f((u16)xv[e]);
        int col = cq + j * 8 + e;
        ov[e] = (short)f2b((v - mean) * rs * ldf(lng, lnOff + col, f) + ldf(lnb, lnOff + col, f));
      }
      *(s16x8*)(g_ws + XOFF + rowg * 256 + cq + j * 8) = ov;
    }
  }
}

// ---------------------------------------------------------------------------
// MFMA attention (S=151 padded 160), VLD/PLD=170 (round-11 bank fix).
// ROUND-14: K staged via global_load_lds (KLD=32, natural 64-B rows; chunk
// swizzle by (j>>1)&3 keeps frag reads at free 2-way). Padded rows j>=151
// read in-bounds finite garbage (g_ws fully written) — masked post-MFMA.
// V keeps the zero-guard (garbage*0 would be fine only if finite... P=0
// exactly for masked cols, but keep zeros for safety).
// ---------------------------------------------------------------------------
#define SP 160
#define KLD 32
#define VLD 170
#define PLD 170

__global__ __launch_bounds__(320) void attn_kernel()
{
  const u16* qkv = g_ws + C1OFF;
  u16* o = g_ws + C2OFF;
  __shared__ __align__(16) u16 Ks[SP * KLD];        // 10240 B
  __shared__ __align__(16) u16 Vt[HD_ * VLD];       // 10880 B
  __shared__ __align__(16) u16 Ps[5][16 * PLD];     // 27200 B
  int bh = blockIdx.x;
  int b = bh >> 3, h = bh & 7;
  int tid = threadIdx.x;
  int lane = tid & 63, wid = tid >> 6;
  const u16* base = qkv + (size_t)b * S_ * 768;

  // Stage K: global_load_lds, 2 groups of 16 rows per wave. Lane l covers
  // row g*16 + (l>>2), d-chunk src = ((l&3) ^ ((l>>3)&3)) (xor-swizzle).
  {
    const int jrow = lane >> 2;
    const int dsw = (((lane & 3) ^ ((lane >> 3) & 3)) * 8);
#pragma unroll
    for (int p = 0; p < 2; p++) {
      int g = wid * 2 + p;                 // 0..9
      int j = g * 16 + jrow;               // 0..159; tail rows masked later
      gload_lds16(base + (size_t)j * 768 + 256 + h * 32 + dsw, &Ks[g * 512]);
    }
  }
  // Stage V transposed (zero-padded).
  for (int g = tid; g < SP * 4; g += 320) {
    int j = g >> 2, d0 = (g & 3) * 8;
    s16x8 vv = {0, 0, 0, 0, 0, 0, 0, 0};
    if (j < S_) vv = *(const s16x8*)(base + (size_t)j * 768 + 512 + h * 32 + d0);
#pragma unroll
    for (int i = 0; i < 8; i++) Vt[(d0 + i) * VLD + j] = (u16)vv[i];
  }
  __syncthreads();   // drains vmcnt (K gloads) + V writes

  const int frow = lane & 15;
  const int quad = lane >> 4;
  const int fk = quad * 8;
  const float scale = 0.17677669529663687f;  // 1/sqrt(32)

  for (int round = 0; round < 2; round++) {
    int mt = round * 5 + wid;
    int qrow = mt * 16 + frow;
    s16x8 aq = {0, 0, 0, 0, 0, 0, 0, 0};
    if (qrow < S_) aq = *(const s16x8*)(base + (size_t)qrow * 768 + h * 32 + fk);
    f32x4 sacc[10];
#pragma unroll
    for (int nt = 0; nt < 10; nt++) {
      // un-swizzle: chunk quad lives at slot quad ^ ((row>>1)&3)
      s16x8 bk = *(const s16x8*)&Ks[(nt * 16 + frow) * KLD
                                    + ((quad ^ ((frow >> 1) & 3)) * 8)];
      f32x4 z = {0.f, 0.f, 0.f, 0.f};
      sacc[nt] = __builtin_amdgcn_mfma_f32_16x16x32_bf16(aq, bk, z, 0, 0, 0);
    }
#pragma unroll
    for (int nt = 0; nt < 10; nt++) {
      int colg = nt * 16 + frow;
      float msk = (colg < S_) ? 1.f : 0.f;
#pragma unroll
      for (int r = 0; r < 4; r++)
        sacc[nt][r] = msk ? sacc[nt][r] * scale : -1e30f;
    }
    float inv[4];
#pragma unroll
    for (int r = 0; r < 4; r++) {
      float mx = -1e30f;
#pragma unroll
      for (int nt = 0; nt < 10; nt++) mx = fmaxf(mx, sacc[nt][r]);
#pragma unroll
      for (int m = 1; m < 16; m <<= 1) mx = fmaxf(mx, __shfl_xor(mx, m, 64));
      float sm2 = 0.f;
#pragma unroll
      for (int nt = 0; nt < 10; nt++) {
        float p = __expf(sacc[nt][r] - mx);
        sacc[nt][r] = p;
        sm2 += p;
      }
#pragma unroll
      for (int m = 1; m < 16; m <<= 1) sm2 += __shfl_xor(sm2, m, 64);
      inv[r] = 1.f / sm2;
    }
#pragma unroll
    for (int nt = 0; nt < 10; nt++)
#pragma unroll
      for (int r = 0; r < 4; r++)
        Ps[wid][(quad * 4 + r) * PLD + nt * 16 + frow] = f2b(sacc[nt][r]);
    f32x4 oacc[2] = {};
#pragma unroll
    for (int ks = 0; ks < 5; ks++) {
      s16x8 ap = *(const s16x8*)&Ps[wid][frow * PLD + ks * 32 + fk];
#pragma unroll
      for (int nt2 = 0; nt2 < 2; nt2++) {
        s16x8 bv = *(const s16x8*)&Vt[(nt2 * 16 + frow) * VLD + ks * 32 + fk];
        oacc[nt2] = __builtin_amdgcn_mfma_f32_16x16x32_bf16(ap, bv, oacc[nt2], 0, 0, 0);
      }
    }
#pragma unroll
    for (int nt2 = 0; nt2 < 2; nt2++)
#pragma unroll
      for (int r = 0; r < 4; r++) {
        int rowg = mt * 16 + quad * 4 + r;
        if (rowg < S_)
          o[(size_t)(b * S_ + rowg) * D_ + h * 32 + nt2 * 16 + frow] = f2b(oacc[nt2][r] * inv[r]);
      }
  }
}

// ---------------------------------------------------------------------------
// Head: cls row -> two LNs (shared stats) -> two tiny matvecs.
// ---------------------------------------------------------------------------
__global__ __launch_bounds__(256) void head_kernel(
    const void* dg, const void* dbt, const void* dW, const void* dbias,
    const void* ag, const void* abt, const void* aW, const void* abias,
    void* out)
{
  const int f = g_f32flag;
  const u16* x = g_ws + XOFF;
  int bg = blockIdx.x;
  int tid = threadIdx.x;
  float c = b2f(x[(size_t)bg * S_ * D_ + tid]);
  float s1 = c, s2 = c * c;
#pragma unroll
  for (int off = 32; off > 0; off >>= 1) {
    s1 += __shfl_down(s1, off, 64);
    s2 += __shfl_down(s2, off, 64);
  }
  __shared__ float ws1[4], ws2[4], stats[2];
  __shared__ float lnD[256], lnA[256];
  int wid = tid >> 6, lane = tid & 63;
  if (lane == 0) { ws1[wid] = s1; ws2[wid] = s2; }
  __syncthreads();
  if (tid == 0) {
    float t1 = ws1[0] + ws1[1] + ws1[2] + ws1[3];
    float t2 = ws2[0] + ws2[1] + ws2[2] + ws2[3];
    float mean = t1 * (1.f / 256.f);
    float var = t2 * (1.f / 256.f) - mean * mean;
    stats[0] = mean;
    stats[1] = rsqrtf(var + 1e-5f);
  }
  __syncthreads();
  float n = (c - stats[0]) * stats[1];
  lnD[tid] = n * ldf(dg, tid, f) + ldf(dbt, tid, f);
  lnA[tid] = n * ldf(ag, tid, f) + ldf(abt, tid, f);
  __syncthreads();
  if (tid < NC_) {
    float acc = ldf(dbias, tid, f);
    for (int k = 0; k < D_; k++) acc += lnD[k] * ldf(dW, k * NC_ + tid, f);
    if (f) ((float*)out)[bg * NC_ + tid] = acc;
    else   ((bf16*)out)[bg * NC_ + tid] = __float2bfloat16(acc);
  } else if (tid == 8) {
    float acc = ldf(abias, 0, f);
    for (int k = 0; k < D_; k++) acc += lnA[k] * ldf(aW, k, f);
    if (f) ((float*)out)[B_ * NC_ + bg] = acc;
    else   ((bf16*)out)[B_ * NC_ + bg] = __float2bfloat16(acc);
  }
}

// ---------------------------------------------------------------------------
extern "C" void kernel_launch(void* const* d_in, const int* in_sizes, int n_in,
                              void* d_out, int out_size, void* d_ws, size_t ws_size,
                              hipStream_t stream)
{
  (void)in_sizes; (void)out_size; (void)d_ws; (void)ws_size;
  if (n_in < 34) return;
  const int* token_types  = (const int*)d_in[0];
  const int* decision_ids = (const int*)d_in[1];

  probe_kernel<<<1, 256, 0, stream>>>(d_in[12]);   // pos_embed

  wtrans_kernel<<<(DEPTH_ * D_ * 768 + 255) / 256, 256, 0, stream>>>(
      d_in[14], QKVT_OFF, D_, 768, DEPTH_ * D_ * 768);
  wtrans_kernel<<<(DEPTH_ * D_ * D_ + 255) / 256, 256, 0, stream>>>(
      d_in[16], OUTT_OFF, D_, D_, DEPTH_ * D_ * D_);
  wtrans_kernel<<<(DEPTH_ * D_ * FF_ + 255) / 256, 256, 0, stream>>>(
      d_in[22], FFN1T_OFF, D_, FF_, DEPTH_ * D_ * FF_);
  wtrans_kernel<<<(DEPTH_ * FF_ * D_ + 255) / 256, 256, 0, stream>>>(
      d_in[24], FFN2T_OFF, FF_, D_, DEPTH_ * FF_ * D_);

  embed_kernel<<<MTOT, 256, 0, stream>>>(token_types, decision_ids,
      d_in[2], d_in[3], d_in[4], d_in[5], d_in[6], d_in[7], d_in[8],
      d_in[9], d_in[10], d_in[11], d_in[12], d_in[13]);

  for (int i = 0; i < DEPTH_; i++) {
    gemm_mfma<<<6 * MT128, 256, 0, stream>>>(XOFF,
        QKVT_OFF + i * D_ * 768, d_in[15], (size_t)i * 768, C1OFF, 768, D_, 0, 6);
    attn_kernel<<<B_ * H_, 320, 0, stream>>>();
    // out-proj fused: x = LN1(x + attn_out @ Wout + b)
    gemm_ln<<<MT64, 256, 0, stream>>>(C2OFF,
        OUTT_OFF + i * D_ * D_, d_in[17], (size_t)i * D_,
        d_in[18], d_in[19], (size_t)i * D_, D_);
    gemm_mfma<<<8 * MT128, 256, 0, stream>>>(XOFF,
        FFN1T_OFF + i * D_ * FF_, d_in[23], (size_t)i * FF_, C1OFF, FF_, D_, 1, 8);
    // ffn2 fused: x = LN2(x + ff @ W2 + b)
    gemm_ln<<<MT64, 256, 0, stream>>>(C1OFF,
        FFN2T_OFF + i * FF_ * D_, d_in[25], (size_t)i * D_,
        d_in[20], d_in[21], (size_t)i * D_, FF_);
  }
  head_kernel<<<B_, 256, 0, stream>>>(d_in[26], d_in[27], d_in[28], d_in[29],
      d_in[30], d_in[31], d_in[32], d_in[33], d_out);
}

// Round 15
// 2590.235 us; speedup vs baseline: 1.2183x; 1.0187x over previous
//
#include <hip/hip_runtime.h>
#include <hip/hip_bf16.h>

typedef __hip_bfloat16 bf16;
typedef unsigned short u16;
typedef __attribute__((ext_vector_type(8))) short s16x8;   // 8 bf16 (4 VGPRs) MFMA frag
typedef __attribute__((ext_vector_type(4))) float f32x4;   // MFMA accumulator

#define B_ 512
#define T_ 150
#define S_ 151
#define D_ 256
#define H_ 8
#define HD_ 32
#define FF_ 1024
#define NC_ 4
#define DEPTH_ 6
#define MTOT 77312            // B_*S_ = 128 * 604 = 64 * 1208
#define MT128 (MTOT / 128)    // 604
#define MT64 (MTOT / 64)      // 1208

// bf16 workspace regions (elements):
#define XOFF 0
#define C1OFF (MTOT * D_)               // x: MTOT*256
#define C2OFF (C1OFF + MTOT * FF_)      // c1: MTOT*1024 (qkv / ffn1 out)
#define WSELEMS (C2OFF + MTOT * D_)     // c2: MTOT*256 (attn out)

// Transposed bf16 weights Wt[N][K], all layers, rebuilt per call:
#define QKVT_OFF 0
#define OUTT_OFF (QKVT_OFF + DEPTH_ * D_ * 768)
#define FFN1T_OFF (OUTT_OFF + DEPTH_ * D_ * D_)
#define FFN2T_OFF (FFN1T_OFF + DEPTH_ * D_ * FF_)
#define WTELEMS (FFN2T_OFF + DEPTH_ * FF_ * D_)    // 9.4 MB

// Static device memory (d_ws proved unusable rounds 1-3).
__device__ __align__(16) u16 g_ws[WSELEMS];
__device__ __align__(16) u16 g_wt[WTELEMS];
__device__ int g_f32flag;   // 1 => external buffers f32, 0 => bf16

__device__ __forceinline__ float ldf(const void* p, size_t i, int f) {
  return f ? ((const float*)p)[i] : __bfloat162float(((const bf16*)p)[i]);
}
__device__ __forceinline__ float b2f(u16 u) {
  union { unsigned int i; float f; } v; v.i = ((unsigned int)u) << 16; return v.f;
}
__device__ __forceinline__ u16 f2b(float x) {
  bf16 h = __float2bfloat16(x);
  return *reinterpret_cast<u16*>(&h);
}

// Async global->LDS, 16 B/lane. LDS dest = wave-uniform base + lane*16.
typedef __attribute__((address_space(3))) void lds_void;
typedef const __attribute__((address_space(1))) void glob_void;
__device__ __forceinline__ void gload_lds16(const u16* g, u16* l) {
  __builtin_amdgcn_global_load_lds((glob_void*)g, (lds_void*)l, 16, 0, 0);
}

// ---------------------------------------------------------------------------
// Dtype probe on pos_embed (38656 elems ~N(0,0.02^2)) viewed as 16-bit words.
// ---------------------------------------------------------------------------
#define PROBE_N 38656
__global__ __launch_bounds__(256) void probe_kernel(const void* pe)
{
  const u16* w = (const u16*)pe;
  int susp = 0, zeroEven = 0;
  for (int k = threadIdx.x; k < PROBE_N; k += 256) {
    u16 u = w[k];
    int ex = (u >> 7) & 0xFF;
    if (ex >= 141) susp++;
    if ((k & 1) == 0 && (u & 0x7FFF) == 0) zeroEven++;
  }
  __shared__ int s_susp, s_zero;
  if (threadIdx.x == 0) { s_susp = 0; s_zero = 0; }
  __syncthreads();
  atomicAdd(&s_susp, susp);
  atomicAdd(&s_zero, zeroEven);
  __syncthreads();
  if (threadIdx.x == 0)
    g_f32flag = (s_susp > 0 || s_zero >= ((PROBE_N / 2) * 9) / 10) ? 1 : 0;
}

// ---------------------------------------------------------------------------
// Weight transpose+convert: Wt[l][n][k] = W[l][k][n] as bf16.
// ---------------------------------------------------------------------------
__global__ __launch_bounds__(256) void wtrans_kernel(const void* src, int dstOff,
                                                     int K, int N, int total)
{
  const int f = g_f32flag;
  int idx = blockIdx.x * 256 + threadIdx.x;
  if (idx >= total) return;
  int kn = K * N;
  int l = idx / kn;
  int r = idx - l * kn;
  int k = r / N;
  int n = r - k * N;
  g_wt[dstOff + (size_t)l * kn + (size_t)n * K + k] = f2b(ldf(src, idx, f));
}

// ---------------------------------------------------------------------------
// Embedding: row = blockIdx.x, writes bf16 x.
// ---------------------------------------------------------------------------
__global__ __launch_bounds__(256) void embed_kernel(
    const int* __restrict__ tt, const int* __restrict__ dids,
    const void* av, const void* dv, const void* vv,
    const void* aW, const void* ab, const void* dW, const void* db,
    const void* vW, const void* vb, const void* table, const void* pos,
    const void* cls)
{
  const int f = g_f32flag;
  u16* x = g_ws + XOFF;
  int row = blockIdx.x;
  int d = threadIdx.x;
  int b = row / S_;
  int s = row - b * S_;
  float val;
  if (s == 0) {
    val = ldf(cls, d, f);
  } else {
    int t = s - 1;
    int idx = b * T_ + t;
    int ty = tt[idx];
    if (ty == 0) {
      val = ldf(av, idx, f) * ldf(aW, d, f) + ldf(ab, d, f);
    } else if (ty == 1) {
      float acc = ldf(db, d, f) + ldf(vb, d, f);
#pragma unroll
      for (int i = 0; i < 10; i++) acc += ldf(dv, (size_t)idx * 10 + i, f) * ldf(dW, i * D_ + d, f);
#pragma unroll
      for (int i = 0; i < 3; i++) acc += ldf(vv, (size_t)idx * 3 + i, f) * ldf(vW, i * D_ + d, f);
      val = acc;
    } else if (ty == 2) {
      int did = dids[idx] & (NC_ - 1);
      val = ldf(table, (size_t)did * D_ + d, f);
    } else {
      val = 0.f;
    }
  }
  val += ldf(pos, s * D_ + d, f);
  x[(size_t)row * D_ + d] = f2b(val);
}

// ---------------------------------------------------------------------------
// MFMA GEMM (round-9 proven): 128x128, BK=64, 256 thr, global_load_lds w=16,
// xor-swizzled chunks (0 conflicts), XCD swizzle, LDS-staged epilogue.
// __launch_bounds__(256,3): verified round 14 (VGPR 112->80, 3 blocks/CU).
// ---------------------------------------------------------------------------
__global__ __launch_bounds__(256, 3) void gemm_mfma(
    int aOff, int wtOff, const void* bias, size_t bOff,
    int cOff, int N, int K, int relu, int NB)
{
  const int f = g_f32flag;
  const u16* A = g_ws + aOff;
  const u16* Bt = g_wt + wtOff;
  u16* C = g_ws + cOff;
  __shared__ __align__(16) u16 sm[16384];
  const int tid = threadIdx.x;

  int gblk = blockIdx.x;
  int bm, bn;
  {
    const int full = (MT128 / 8) * 8;        // 600
    if (gblk < NB * full) {
      int per = NB * 8;
      int grp = gblk / per, rem = gblk % per;
      bm = grp * 8 + (rem & 7);
      bn = rem >> 3;
    } else {
      int id = gblk - NB * full;
      bm = full + id / NB;
      bn = id % NB;
    }
  }

  const int lane = tid & 63, wid = tid >> 6;
  const int wm = (wid >> 1) * 64, wn = (wid & 1) * 64;
  const int frow = lane & 15, quad = lane >> 4;

  const int rg = lane >> 3;
  const int ck = ((lane & 7) ^ rg) * 8;
  const u16* Ag[4]; const u16* Bg[4];
  u16 *Asl[4], *Bsl[4];
#pragma unroll
  for (int p = 0; p < 4; p++) {
    int grp = wid * 4 + p;
    int row = grp * 8 + rg;
    Ag[p] = A + (size_t)(bm * 128 + row) * K + ck;
    Bg[p] = Bt + (size_t)(bn * 128 + row) * K + ck;
    Asl[p] = &sm[grp * 512];
    Bsl[p] = &sm[8192 + grp * 512];
  }

  f32x4 acc[4][4] = {};

  for (int kt = 0; kt < K; kt += 64) {
    if (kt) __syncthreads();
#pragma unroll
    for (int p = 0; p < 4; p++) {
      gload_lds16(Ag[p] + kt, Asl[p]);
      gload_lds16(Bg[p] + kt, Bsl[p]);
    }
    __syncthreads();
#pragma unroll
    for (int s = 0; s < 2; s++) {
      s16x8 af[4], bfr[4];
      const int cfr = ((s * 4 + quad) ^ (frow & 7)) * 8;
#pragma unroll
      for (int t = 0; t < 4; t++) {
        af[t]  = *(const s16x8*)&sm[(wm + t * 16 + frow) * 64 + cfr];
        bfr[t] = *(const s16x8*)&sm[8192 + (wn + t * 16 + frow) * 64 + cfr];
      }
#pragma unroll
      for (int mt = 0; mt < 4; mt++)
#pragma unroll
        for (int nt = 0; nt < 4; nt++)
          acc[mt][nt] = __builtin_amdgcn_mfma_f32_16x16x32_bf16(af[mt], bfr[nt], acc[mt][nt], 0, 0, 0);
    }
  }

  float bv[4];
#pragma unroll
  for (int nt = 0; nt < 4; nt++)
    bv[nt] = ldf(bias, bOff + (size_t)(bn * 128 + wn + nt * 16 + frow), f);
  __syncthreads();
#pragma unroll
  for (int p = 0; p < 2; p++) {
    if ((wid >> 1) == p) {
#pragma unroll
      for (int mt = 0; mt < 4; mt++)
#pragma unroll
        for (int nt = 0; nt < 4; nt++)
#pragma unroll
          for (int r = 0; r < 4; r++) {
            int rl = (wm & 63) + mt * 16 + quad * 4 + r;
            float v = acc[mt][nt][r] + bv[nt];
            if (relu) v = fmaxf(v, 0.f);
            sm[rl * 136 + wn + nt * 16 + frow] = f2b(v);
          }
    }
    __syncthreads();
    {
      int rl = tid >> 2;
      int cq = (tid & 3) * 32;
      size_t gb = (size_t)(bm * 128 + p * 64 + rl) * N + bn * 128 + cq;
#pragma unroll
      for (int j = 0; j < 4; j++)
        *(s16x8*)(C + gb + j * 8) = *(const s16x8*)&sm[rl * 136 + cq + j * 8];
    }
    __syncthreads();
  }
}

// ---------------------------------------------------------------------------
// Fused-LN GEMM: x = LN(x + A@W + bias) * g + b. 64x256 tile, 256 thr =
// 4 waves side-by-side in N. Single-phase K-loop (round-12 lesson).
// ROUND-15: __launch_bounds__(256,4) — 68 VGPR + 64 AGPR = 132 unified is
// 4 over the 128 needed for 4 waves/SIMD; LDS (40KB) allows exactly 4
// blocks/CU. If this spills and regresses, revert to (256,3).
// ---------------------------------------------------------------------------
__global__ __launch_bounds__(256, 4) void gemm_ln(
    int aOff, int wtOff, const void* bias, size_t bOff,
    const void* lng, const void* lnb, size_t lnOff, int K)
{
  const int f = g_f32flag;
  const u16* A = g_ws + aOff;
  const u16* Bt = g_wt + wtOff;
  __shared__ __align__(16) u16 sm[20480];   // A 8KB | B 32KB; epilogue 64x264
  const int tid = threadIdx.x;
  const int bm = blockIdx.x;                // 64-row tile
  const int lane = tid & 63, wid = tid >> 6;
  const int wn = wid * 64;
  const int frow = lane & 15, quad = lane >> 4;
  const int rg = lane >> 3;
  const int ck = ((lane & 7) ^ rg) * 8;

  const u16* Ag[2]; u16* Asl[2];
  const u16* Bg[8]; u16* Bsl[8];
#pragma unroll
  for (int p = 0; p < 2; p++) {
    int grp = wid * 2 + p;                  // 0..8: rows 0..63
    Ag[p] = A + (size_t)(bm * 64 + grp * 8 + rg) * K + ck;
    Asl[p] = &sm[grp * 512];
  }
#pragma unroll
  for (int p = 0; p < 8; p++) {
    int grp = wid * 8 + p;                  // 0..32: Wt rows 0..255
    Bg[p] = Bt + (size_t)(grp * 8 + rg) * K + ck;
    Bsl[p] = &sm[4096 + grp * 512];
  }

  f32x4 acc[4][4] = {};

  for (int kt = 0; kt < K; kt += 64) {
    if (kt) __syncthreads();
#pragma unroll
    for (int p = 0; p < 2; p++) gload_lds16(Ag[p] + kt, Asl[p]);
#pragma unroll
    for (int p = 0; p < 8; p++) gload_lds16(Bg[p] + kt, Bsl[p]);
    __syncthreads();
#pragma unroll
    for (int s = 0; s < 2; s++) {
      s16x8 af[4], bfr[4];
      const int cfr = ((s * 4 + quad) ^ (frow & 7)) * 8;
#pragma unroll
      for (int t = 0; t < 4; t++) {
        af[t]  = *(const s16x8*)&sm[(t * 16 + frow) * 64 + cfr];
        bfr[t] = *(const s16x8*)&sm[4096 + (wn + t * 16 + frow) * 64 + cfr];
      }
#pragma unroll
      for (int mt = 0; mt < 4; mt++)
#pragma unroll
        for (int nt = 0; nt < 4; nt++)
          acc[mt][nt] = __builtin_amdgcn_mfma_f32_16x16x32_bf16(af[mt], bfr[nt], acc[mt][nt], 0, 0, 0);
    }
  }

  float bv[4];
#pragma unroll
  for (int nt = 0; nt < 4; nt++)
    bv[nt] = ldf(bias, bOff + (size_t)(wn + nt * 16 + frow), f);
  __syncthreads();   // all frag reads done; reuse sm as y-buf 64x264
#pragma unroll
  for (int mt = 0; mt < 4; mt++)
#pragma unroll
    for (int nt = 0; nt < 4; nt++)
#pragma unroll
      for (int r = 0; r < 4; r++) {
        int row = mt * 16 + quad * 4 + r;
        int col = wn + nt * 16 + frow;
        sm[row * 264 + col] = f2b(acc[mt][nt][r] + bv[nt]);
      }
  __syncthreads();
  {
    int rl = tid >> 2;                 // row 0..63 (4 lanes per row)
    int cq = (tid & 3) * 64;           // 64 cols per lane
    size_t rowg = (size_t)bm * 64 + rl;
    float s1 = 0.f, s2 = 0.f;
#pragma unroll
    for (int j = 0; j < 8; j++) {
      s16x8 yv = *(const s16x8*)&sm[rl * 264 + cq + j * 8];
      s16x8 xv = *(const s16x8*)(g_ws + XOFF + rowg * 256 + cq + j * 8);
#pragma unroll
      for (int e = 0; e < 8; e++) {
        float v = b2f((u16)yv[e]) + b2f((u16)xv[e]);
        s1 += v; s2 += v * v;
      }
    }
    s1 += __shfl_xor(s1, 1, 64); s2 += __shfl_xor(s2, 1, 64);
    s1 += __shfl_xor(s1, 2, 64); s2 += __shfl_xor(s2, 2, 64);
    float mean = s1 * (1.f / 256.f);
    float var = s2 * (1.f / 256.f) - mean * mean;
    float rs = rsqrtf(var + 1e-5f);
#pragma unroll
    for (int j = 0; j < 8; j++) {
      s16x8 yv = *(const s16x8*)&sm[rl * 264 + cq + j * 8];
      s16x8 xv = *(const s16x8*)(g_ws + XOFF + rowg * 256 + cq + j * 8);
      s16x8 ov;
#pragma unroll
      for (int e = 0; e < 8; e++) {
        float v = b2f((u16)yv[e]) + b2f((u16)xv[e]);
        int col = cq + j * 8 + e;
        ov[e] = (short)f2b((v - mean) * rs * ldf(lng, lnOff + col, f) + ldf(lnb, lnOff + col, f));
      }
      *(s16x8*)(g_ws + XOFF + rowg * 256 + cq + j * 8) = ov;
    }
  }
}

// ---------------------------------------------------------------------------
// MFMA attention (S=151 padded 160). K staged via global_load_lds (KLD=32,
// xor-swizzle; round-14 verified). ROUND-15: interleaved P-transpose — per
// 32-key chunk, write the 16x32 P slice into a small wave-private buffer
// (stride 42: quad banks 0/20/8/28 distinct) and immediately run the PV
// MFMAs (same-wave LDS ordering is in-order). Ps shrinks 27.2KB -> 6.7KB;
// block LDS 48.3 -> 27.8 KB => 5 blocks/CU (was 3).
// ---------------------------------------------------------------------------
#define SP 160
#define KLD 32
#define VLD 170
#define PLDS 42

__global__ __launch_bounds__(320) void attn_kernel()
{
  const u16* qkv = g_ws + C1OFF;
  u16* o = g_ws + C2OFF;
  __shared__ __align__(16) u16 Ks[SP * KLD];        // 10240 B
  __shared__ __align__(16) u16 Vt[HD_ * VLD];       // 10880 B
  __shared__ __align__(16) u16 Ps[5][16 * PLDS];    // 6720 B
  int bh = blockIdx.x;
  int b = bh >> 3, h = bh & 7;
  int tid = threadIdx.x;
  int lane = tid & 63, wid = tid >> 6;
  const u16* base = qkv + (size_t)b * S_ * 768;

  // Stage K: global_load_lds, 2 groups of 16 rows per wave (xor-swizzled).
  {
    const int jrow = lane >> 2;
    const int dsw = (((lane & 3) ^ ((lane >> 3) & 3)) * 8);
#pragma unroll
    for (int p = 0; p < 2; p++) {
      int g = wid * 2 + p;                 // 0..9
      int j = g * 16 + jrow;               // 0..159; tail rows masked later
      gload_lds16(base + (size_t)j * 768 + 256 + h * 32 + dsw, &Ks[g * 512]);
    }
  }
  // Stage V transposed (zero-padded).
  for (int g = tid; g < SP * 4; g += 320) {
    int j = g >> 2, d0 = (g & 3) * 8;
    s16x8 vv = {0, 0, 0, 0, 0, 0, 0, 0};
    if (j < S_) vv = *(const s16x8*)(base + (size_t)j * 768 + 512 + h * 32 + d0);
#pragma unroll
    for (int i = 0; i < 8; i++) Vt[(d0 + i) * VLD + j] = (u16)vv[i];
  }
  __syncthreads();   // drains vmcnt (K gloads) + V writes

  const int frow = lane & 15;
  const int quad = lane >> 4;
  const int fk = quad * 8;
  const float scale = 0.17677669529663687f;  // 1/sqrt(32)
  u16* Pw = &Ps[wid][0];

  for (int round = 0; round < 2; round++) {
    int mt = round * 5 + wid;
    int qrow = mt * 16 + frow;
    s16x8 aq = {0, 0, 0, 0, 0, 0, 0, 0};
    if (qrow < S_) aq = *(const s16x8*)(base + (size_t)qrow * 768 + h * 32 + fk);
    f32x4 sacc[10];
#pragma unroll
    for (int nt = 0; nt < 10; nt++) {
      // un-swizzle: chunk quad lives at slot quad ^ ((row>>1)&3)
      s16x8 bk = *(const s16x8*)&Ks[(nt * 16 + frow) * KLD
                                    + ((quad ^ ((frow >> 1) & 3)) * 8)];
      f32x4 z = {0.f, 0.f, 0.f, 0.f};
      sacc[nt] = __builtin_amdgcn_mfma_f32_16x16x32_bf16(aq, bk, z, 0, 0, 0);
    }
#pragma unroll
    for (int nt = 0; nt < 10; nt++) {
      int colg = nt * 16 + frow;
      float msk = (colg < S_) ? 1.f : 0.f;
#pragma unroll
      for (int r = 0; r < 4; r++)
        sacc[nt][r] = msk ? sacc[nt][r] * scale : -1e30f;
    }
    float inv[4];
#pragma unroll
    for (int r = 0; r < 4; r++) {
      float mx = -1e30f;
#pragma unroll
      for (int nt = 0; nt < 10; nt++) mx = fmaxf(mx, sacc[nt][r]);
#pragma unroll
      for (int m = 1; m < 16; m <<= 1) mx = fmaxf(mx, __shfl_xor(mx, m, 64));
      float sm2 = 0.f;
#pragma unroll
      for (int nt = 0; nt < 10; nt++) {
        float p = __expf(sacc[nt][r] - mx);
        sacc[nt][r] = p;
        sm2 += p;
      }
#pragma unroll
      for (int m = 1; m < 16; m <<= 1) sm2 += __shfl_xor(sm2, m, 64);
      inv[r] = 1.f / sm2;
    }
    // Interleaved C->A transform + PV: one 32-key chunk at a time through
    // the small wave-private buffer (in-order same-wave LDS ops).
    f32x4 oacc[2] = {};
#pragma unroll
    for (int ks = 0; ks < 5; ks++) {
#pragma unroll
      for (int h2 = 0; h2 < 2; h2++) {
        int nt = ks * 2 + h2;
#pragma unroll
        for (int r = 0; r < 4; r++)
          Pw[(quad * 4 + r) * PLDS + h2 * 16 + frow] = f2b(sacc[nt][r]);
      }
      s16x8 ap = *(const s16x8*)&Pw[frow * PLDS + fk];
#pragma unroll
      for (int nt2 = 0; nt2 < 2; nt2++) {
        s16x8 bv = *(const s16x8*)&Vt[(nt2 * 16 + frow) * VLD + ks * 32 + fk];
        oacc[nt2] = __builtin_amdgcn_mfma_f32_16x16x32_bf16(ap, bv, oacc[nt2], 0, 0, 0);
      }
    }
#pragma unroll
    for (int nt2 = 0; nt2 < 2; nt2++)
#pragma unroll
      for (int r = 0; r < 4; r++) {
        int rowg = mt * 16 + quad * 4 + r;
        if (rowg < S_)
          o[(size_t)(b * S_ + rowg) * D_ + h * 32 + nt2 * 16 + frow] = f2b(oacc[nt2][r] * inv[r]);
      }
  }
}

// ---------------------------------------------------------------------------
// Head: cls row -> two LNs (shared stats) -> two tiny matvecs.
// ---------------------------------------------------------------------------
__global__ __launch_bounds__(256) void head_kernel(
    const void* dg, const void* dbt, const void* dW, const void* dbias,
    const void* ag, const void* abt, const void* aW, const void* abias,
    void* out)
{
  const int f = g_f32flag;
  const u16* x = g_ws + XOFF;
  int bg = blockIdx.x;
  int tid = threadIdx.x;
  float c = b2f(x[(size_t)bg * S_ * D_ + tid]);
  float s1 = c, s2 = c * c;
#pragma unroll
  for (int off = 32; off > 0; off >>= 1) {
    s1 += __shfl_down(s1, off, 64);
    s2 += __shfl_down(s2, off, 64);
  }
  __shared__ float ws1[4], ws2[4], stats[2];
  __shared__ float lnD[256], lnA[256];
  int wid = tid >> 6, lane = tid & 63;
  if (lane == 0) { ws1[wid] = s1; ws2[wid] = s2; }
  __syncthreads();
  if (tid == 0) {
    float t1 = ws1[0] + ws1[1] + ws1[2] + ws1[3];
    float t2 = ws2[0] + ws2[1] + ws2[2] + ws2[3];
    float mean = t1 * (1.f / 256.f);
    float var = t2 * (1.f / 256.f) - mean * mean;
    stats[0] = mean;
    stats[1] = rsqrtf(var + 1e-5f);
  }
  __syncthreads();
  float n = (c - stats[0]) * stats[1];
  lnD[tid] = n * ldf(dg, tid, f) + ldf(dbt, tid, f);
  lnA[tid] = n * ldf(ag, tid, f) + ldf(abt, tid, f);
  __syncthreads();
  if (tid < NC_) {
    float acc = ldf(dbias, tid, f);
    for (int k = 0; k < D_; k++) acc += lnD[k] * ldf(dW, k * NC_ + tid, f);
    if (f) ((float*)out)[bg * NC_ + tid] = acc;
    else   ((bf16*)out)[bg * NC_ + tid] = __float2bfloat16(acc);
  } else if (tid == 8) {
    float acc = ldf(abias, 0, f);
    for (int k = 0; k < D_; k++) acc += lnA[k] * ldf(aW, k, f);
    if (f) ((float*)out)[B_ * NC_ + bg] = acc;
    else   ((bf16*)out)[B_ * NC_ + bg] = __float2bfloat16(acc);
  }
}

// ---------------------------------------------------------------------------
extern "C" void kernel_launch(void* const* d_in, const int* in_sizes, int n_in,
                              void* d_out, int out_size, void* d_ws, size_t ws_size,
                              hipStream_t stream)
{
  (void)in_sizes; (void)out_size; (void)d_ws; (void)ws_size;
  if (n_in < 34) return;
  const int* token_types  = (const int*)d_in[0];
  const int* decision_ids = (const int*)d_in[1];

  probe_kernel<<<1, 256, 0, stream>>>(d_in[12]);   // pos_embed

  wtrans_kernel<<<(DEPTH_ * D_ * 768 + 255) / 256, 256, 0, stream>>>(
      d_in[14], QKVT_OFF, D_, 768, DEPTH_ * D_ * 768);
  wtrans_kernel<<<(DEPTH_ * D_ * D_ + 255) / 256, 256, 0, stream>>>(
      d_in[16], OUTT_OFF, D_, D_, DEPTH_ * D_ * D_);
  wtrans_kernel<<<(DEPTH_ * D_ * FF_ + 255) / 256, 256, 0, stream>>>(
      d_in[22], FFN1T_OFF, D_, FF_, DEPTH_ * D_ * FF_);
  wtrans_kernel<<<(DEPTH_ * FF_ * D_ + 255) / 256, 256, 0, stream>>>(
      d_in[24], FFN2T_OFF, FF_, D_, DEPTH_ * FF_ * D_);

  embed_kernel<<<MTOT, 256, 0, stream>>>(token_types, decision_ids,
      d_in[2], d_in[3], d_in[4], d_in[5], d_in[6], d_in[7], d_in[8],
      d_in[9], d_in[10], d_in[11], d_in[12], d_in[13]);

  for (int i = 0; i < DEPTH_; i++) {
    gemm_mfma<<<6 * MT128, 256, 0, stream>>>(XOFF,
        QKVT_OFF + i * D_ * 768, d_in[15], (size_t)i * 768, C1OFF, 768, D_, 0, 6);
    attn_kernel<<<B_ * H_, 320, 0, stream>>>();
    // out-proj fused: x = LN1(x + attn_out @ Wout + b)
    gemm_ln<<<MT64, 256, 0, stream>>>(C2OFF,
        OUTT_OFF + i * D_ * D_, d_in[17], (size_t)i * D_,
        d_in[18], d_in[19], (size_t)i * D_, D_);
    gemm_mfma<<<8 * MT128, 256, 0, stream>>>(XOFF,
        FFN1T_OFF + i * D_ * FF_, d_in[23], (size_t)i * FF_, C1OFF, FF_, D_, 1, 8);
    // ffn2 fused: x = LN2(x + ff @ W2 + b)
    gemm_ln<<<MT64, 256, 0, stream>>>(C1OFF,
        FFN2T_OFF + i * FF_ * D_, d_in[25], (size_t)i * D_,
        d_in[20], d_in[21], (size_t)i * D_, FF_);
  }
  head_kernel<<<B_, 256, 0, stream>>>(d_in[26], d_in[27], d_in[28], d_in[29],
      d_in[30], d_in[31], d_in[32], d_in[33], d_out);
}